// Round 10
// baseline (504.237 us; speedup 1.0000x reference)
//
#include <hip/hip_runtime.h>

#define TDIM 2048
#define CDIM 512
#define BDIM 8
#define PDIM 512
#define DMODEL 512
#define NCOUT 30
#define SPPOUT 3584
#define AKDIM 4096   // SPPOUT + DMODEL

typedef __attribute__((ext_vector_type(8))) short short8;
typedef __attribute__((ext_vector_type(4))) short short4v;
typedef __attribute__((ext_vector_type(2))) short short2v;
typedef __attribute__((ext_vector_type(4))) float f32x4;

typedef const __attribute__((address_space(1))) void* as1cv;
typedef __attribute__((address_space(3))) void* as3v;

// async global->LDS, 16B per lane; LDS dest must be wave-uniform base + lane*16
__device__ __forceinline__ void gl_lds16(const short* g, short* l){
  __builtin_amdgcn_global_load_lds((as1cv)g, (as3v)l, 16, 0, 0);
}

__device__ __forceinline__ short f2b(float f){
  unsigned u = __float_as_uint(f);
  unsigned r = (u + 0x7fffu + ((u >> 16) & 1u)) >> 16;
  return (short)r;
}
__device__ __forceinline__ float b2f(unsigned short u){
  return __uint_as_float(((unsigned)u) << 16);
}

__device__ __forceinline__ float waveSum(float v){
#pragma unroll
  for (int o = 32; o > 0; o >>= 1) v += __shfl_xor(v, o);
  return v;
}
__device__ __forceinline__ float waveMax(float v){
#pragma unroll
  for (int o = 32; o > 0; o >>= 1) v = fmaxf(v, __shfl_xor(v, o));
  return v;
}

// ---- merged front kernel: blocks [0,256) scan | [256,264) sort | [264,..) weight prep ----
// scan: 32 chunks of 64 along T (1 block/CU): csum[b][t][c], tot[b][ch][c]
// prep: float4/short4 vectorized (all section boundaries 4-aligned)
__global__ __launch_bounds__(512) void k0(
    const float* __restrict__ x, const int* __restrict__ boxes,
    const float* __restrict__ pw, const float* __restrict__ pw2,
    const float* __restrict__ qw, const float* __restrict__ ow,
    const float* __restrict__ f1, const float* __restrict__ f2,
    const float* __restrict__ cl, const float* __restrict__ dt,
    const float* __restrict__ pb, const float* __restrict__ pb2,
    const float* __restrict__ cb, const float* __restrict__ db,
    float* __restrict__ W, float* __restrict__ tot,
    int* __restrict__ sidx, float* __restrict__ out,
    short* __restrict__ Wc, short* __restrict__ Wd,
    float* __restrict__ bc, float* __restrict__ bh)
{
  __shared__ unsigned key[PDIM];
  int blk = blockIdx.x, t = threadIdx.x;
  if (blk < 256){
    int b = blk >> 5, ch = blk & 31;
    int c = t;
    const float* xp = x + ((size_t)(b * CDIM + c)) * TDIM + ch * 64;
    float* wp = W + ((size_t)b * TDIM + ch * 64) * CDIM + c;
    float run = 0.f;
    for (int tl = 0; tl < 64; tl += 4){
      float4 v = *(const float4*)(xp + tl);
      run += v.x; wp[(size_t)(tl + 0) * CDIM] = run;
      run += v.y; wp[(size_t)(tl + 1) * CDIM] = run;
      run += v.z; wp[(size_t)(tl + 2) * CDIM] = run;
      run += v.w; wp[(size_t)(tl + 3) * CDIM] = run;
    }
    tot[((size_t)b * 32 + ch) * CDIM + c] = run;
  } else if (blk < 264){
    int b = blk - 256;
    if (b == 0 && t < 240) out[t] = 0.f;
    int s = boxes[(size_t)(b * PDIM + t) * 2];
    int e = boxes[(size_t)(b * PDIM + t) * 2 + 1];
    key[t] = ((unsigned)(s + e) << 9) | (unsigned)t;
    __syncthreads();
    for (int k = 2; k <= PDIM; k <<= 1){
      for (int j = k >> 1; j > 0; j >>= 1){
        int ixj = t ^ j;
        if (ixj > t){
          unsigned a = key[t], c2 = key[ixj];
          bool up = ((t & k) == 0);
          bool doswap = up ? (a > c2) : (a < c2);
          if (doswap){ key[t] = c2; key[ixj] = a; }
        }
        __syncthreads();
      }
    }
    sidx[b * PDIM + t] = (int)(key[t] & 511u);
  } else {
    int i4 = (blk - 264) * 512 + t;
    if (i4 < 524288){                       // Wc: elements [0, 2097152), 4 per slot
      int base = i4 * 4;
      int r = base >> 12, k = base & 4095;
      float4 v;
      if (k < SPPOUT) v = *(const float4*)(pw + (size_t)r * SPPOUT + k);
      else            v = *(const float4*)(pw2 + (size_t)r * DMODEL + (k - SPPOUT));
      short4v s = { f2b(v.x), f2b(v.y), f2b(v.z), f2b(v.w) };
      *(short4v*)(Wc + base) = s;
    } else if (i4 < 1580544){               // Wd: j in [0, 4225024), 4 per slot
      int j = i4 * 4 - 2097152;
      const float* src; int off;
      if (j < 1572864){ src = qw; off = j; }
      else if (j < 2097152){ src = ow; off = j - 1572864; }
      else if (j < 3145728){ src = f1; off = j - 2097152; }
      else if (j < 4194304){ src = f2; off = j - 3145728; }
      else if (j < 4209664){ src = cl; off = j - 4194304; }
      else { src = dt; off = j - 4209664; }
      float4 v = *(const float4*)(src + off);
      short4v s = { f2b(v.x), f2b(v.y), f2b(v.z), f2b(v.w) };
      *(short4v*)(Wd + j) = s;
    } else if (i4 < 1580688){               // biases: k in [0,576)
      int k = (i4 - 1580544) * 4;
#pragma unroll
      for (int u = 0; u < 4; ++u){
        int kk = k + u;
        if (kk < 512) bc[kk] = pb[kk] + pb2[kk];
        else if (kk < 572) bh[kk - 512] = (kk < 542) ? cb[kk - 512] : db[kk - 542];
      }
    }
  }
}

// exclusive prefix of per-chunk totals -> off[b][ch][c], 32 chunks
__global__ void koff(const float* __restrict__ tot, float* __restrict__ off){
  int b = blockIdx.x >> 1, cg = blockIdx.x & 1;
  int c = cg * 256 + threadIdx.x;
  float run = 0.f;
  for (int ch = 0; ch < 32; ++ch){
    off[((size_t)b * 32 + ch) * CDIM + c] = run;
    run += tot[((size_t)b * 32 + ch) * CDIM + c];
  }
}

// SPP pooling + pos-MLP hidden, staged in sorted order as bf16: A[b][j][0..4095]
// Zero LDS (max occupancy); 10 dedup'd prefix rows; uniform reciprocals.
__global__ void kspp(const float* __restrict__ W, const float* __restrict__ off,
                     const int* __restrict__ boxes, const int* __restrict__ sidx,
                     const float* __restrict__ pw1, const float* __restrict__ pb1,
                     short* __restrict__ A){
  int blk = blockIdx.x;
  int b = blk >> 9, j = blk & 511;
  int p = sidx[b * PDIM + j];
  int s0 = boxes[(size_t)(b * PDIM + p) * 2];
  int e0 = boxes[(size_t)(b * PDIM + p) * 2 + 1];
  int start = min(max(s0, 0), TDIM - 1);
  int end   = min(max(e0, 1), TDIM);
  if (end <= start) end = min(start + 1, TDIM);
  int n = end - start;

  int lo[7], hi[7];
  {
    const int Ls[3] = {1, 2, 4};
    int q = 0;
    for (int li = 0; li < 3; ++li){
      int L = Ls[li];
      for (int i = 0; i < L; ++i){
        lo[q] = start + (i * n) / L;
        hi[q] = start + ((i + 1) * n + L - 1) / L;
        ++q;
      }
    }
  }
  float inv[7];
#pragma unroll
  for (int q = 0; q < 7; ++q) inv[q] = 1.f / (float)(hi[q] - lo[q]);

  // 10 distinct prefix rows; F(-1) = 0. (F(start-1) used 3x, F(end-1) used 3x)
  int R[10] = { start - 1, end - 1, hi[1] - 1, lo[2] - 1, hi[3] - 1,
                lo[4] - 1, hi[4] - 1, lo[5] - 1, hi[5] - 1, lo[6] - 1 };

  float s_f = (float)s0, e_f = (float)e0;
  float px = (s_f + e_f) * 0.5f / (float)TDIM;
  float py = fmaxf(e_f - s_f, 1.f) / (float)TDIM;
  short* Ar = A + (size_t)(b * PDIM + j) * AKDIM;
  const float* Wb = W + (size_t)b * TDIM * CDIM;
  const float* ob = off + (size_t)b * 32 * CDIM;
#pragma unroll
  for (int cc = 0; cc < 2; ++cc){
    int c = threadIdx.x + cc * 256;
    float F[10];
#pragma unroll
    for (int u = 0; u < 10; ++u){
      int r = R[u];
      F[u] = (r < 0) ? 0.f : (Wb[(size_t)r * CDIM + c] + ob[(r >> 6) * CDIM + c]);
    }
    Ar[c]              = f2b((F[1] - F[0]) * inv[0]);
    Ar[512  + c * 2]   = f2b((F[2] - F[0]) * inv[1]);
    Ar[513  + c * 2]   = f2b((F[1] - F[3]) * inv[2]);
    Ar[1536 + c * 4]   = f2b((F[4] - F[0]) * inv[3]);
    Ar[1537 + c * 4]   = f2b((F[6] - F[5]) * inv[4]);
    Ar[1538 + c * 4]   = f2b((F[8] - F[7]) * inv[5]);
    Ar[1539 + c * 4]   = f2b((F[1] - F[9]) * inv[6]);
    float hv = pw1[c * 2] * px + pw1[c * 2 + 1] * py + pb1[c];
    Ar[SPPOUT + c] = f2b(fmaxf(hv, 0.f));
  }
}

// MFMA bf16 GEMM (nt): C[M,N] = act(alpha * A[M,K] @ B[N,K]^T + bias + resid)
// 128-row tiles, BK=64, XOR-swizzled LDS (conflict-free frag reads).
// SWZ=1: XCD-locality remap (row-chunked, bijective); requires gridDim.y % 8 == 0.
// Vtp: if set and colBase>=1024 (qkv call), the block's output is the V part ->
//      transpose via LDS and store coalesced into Vt[b*4+h][128][512] (skips Cb write).
template<int BN, int SWZ = 0>
__global__ __launch_bounds__(256) void gemm_bt(
    int M, int N, int K,
    const short* __restrict__ A, int lda, long long sAb, long long sAh,
    const short* __restrict__ B, int ldb, long long sBb, long long sBh,
    float* __restrict__ Cf, short* __restrict__ Cb, int ldc, long long sCb, long long sCh,
    int hdiv, float alpha,
    const float* __restrict__ bias, const float* __restrict__ resid, int act,
    short* __restrict__ Vtp)
{
  constexpr int JF = BN / 32;                 // B-frags per wave / B staging batches
  __shared__ short smem[128 * 64 + BN * 64];
  short* As = smem;
  short* Bs = smem + 128 * 64;
  int bx = blockIdx.x, by = blockIdx.y, bz = blockIdx.z;
  if constexpr (SWZ){
    // each XCD owns ny/8 consecutive row-strips across all bx,bz (A-slab L2 reuse)
    int nx = gridDim.x, ny = gridDim.y;
    int rt = ny >> 3;
    int flat = (bz * ny + by) * nx + bx;
    int xcd = flat & 7, wl = flat >> 3;
    by = xcd * rt + wl % rt;
    int rest = wl / rt;
    bx = rest % nx;
    bz = rest / nx;
  }
  int zb = bz / hdiv, zh = bz - zb * hdiv;
  A += (size_t)zb * sAb + (size_t)zh * sAh;
  B += (size_t)zb * sBb + (size_t)zh * sBh;
  size_t coff = (size_t)zb * sCb + (size_t)zh * sCh;
  int rowBase = by * 128, colBase = bx * BN;
  int t = threadIdx.x;
  int lane = t & 63;
  int wave = t >> 6;
  int wm = (wave >> 1) * 64, wn = (wave & 1) * (BN / 2);
  int lm = lane & 15, quad = lane >> 4;
  int srow = t >> 3;
  int skw = ((t & 7) * 8) ^ ((srow & 7) * 8);

  const short* Agp[4];
#pragma unroll
  for (int it = 0; it < 4; ++it)
    Agp[it] = A + (size_t)min(rowBase + srow + it * 32, M - 1) * lda + skw;
  const short* Bgp[JF];
#pragma unroll
  for (int it = 0; it < JF; ++it)
    Bgp[it] = B + (size_t)min(colBase + srow + it * 32, N - 1) * ldb + skw;

  f32x4 zero4 = {0.f, 0.f, 0.f, 0.f};
  f32x4 acc[4][JF];
#pragma unroll
  for (int i = 0; i < 4; ++i)
#pragma unroll
    for (int j = 0; j < JF; ++j) acc[i][j] = zero4;

  int axr = (lm & 7) * 8;
  for (int k0 = 0; k0 < K; k0 += 64){
#pragma unroll
    for (int it = 0; it < 4; ++it) gl_lds16(Agp[it] + k0, As + it * 2048 + t * 8);
#pragma unroll
    for (int it = 0; it < JF; ++it) gl_lds16(Bgp[it] + k0, Bs + it * 2048 + t * 8);
    __syncthreads();
#pragma unroll
    for (int h = 0; h < 2; ++h){
      int koff = (h * 32 + quad * 8) ^ axr;
      short8 af[4], bfr[JF];
#pragma unroll
      for (int i = 0; i < 4; ++i)
        af[i] = *(const short8*)(As + (wm + i * 16 + lm) * 64 + koff);
#pragma unroll
      for (int j = 0; j < JF; ++j)
        bfr[j] = *(const short8*)(Bs + (wn + j * 16 + lm) * 64 + koff);
#pragma unroll
      for (int i = 0; i < 4; ++i)
#pragma unroll
        for (int j = 0; j < JF; ++j)
          acc[i][j] = __builtin_amdgcn_mfma_f32_16x16x32_bf16(af[i], bfr[j], acc[i][j], 0, 0, 0);
    }
    __syncthreads();
  }

  if (Vtp && colBase >= 1024){
    // whole-block V output: bf16-transpose in LDS (pitch 132 kills bank conflicts),
    // then coalesced 64B-per-thread stores into Vt[b*4+h][d][p].
    short* LT = smem;
#pragma unroll
    for (int i = 0; i < 4; ++i){
#pragma unroll
      for (int j = 0; j < JF; ++j){
        int d = wn + j * 16 + lm;
        int prow = wm + i * 16 + quad * 4;
        short4v pk;
#pragma unroll
        for (int r = 0; r < 4; ++r){
          float v = acc[i][j][r] * alpha;
          if (bias) v += bias[colBase + d];
          pk[r] = f2b(v);
        }
        *(short4v*)(LT + d * 132 + prow) = pk;
      }
    }
    __syncthreads();
    int bb = rowBase >> 9;
    int hh = (colBase - 1024) >> 7;
    int dd0 = (colBase - 1024) & 127;
    int dl = t >> 2, pl = (t & 3) * 32;
    const short* sp = LT + dl * 132 + pl;
    short* dp = Vtp + ((size_t)(bb * 4 + hh)) * 65536 + (size_t)(dd0 + dl) * 512 + (rowBase & 511) + pl;
#pragma unroll
    for (int u = 0; u < 4; ++u) *(short8*)(dp + u * 8) = *(const short8*)(sp + u * 8);
    return;
  }

#pragma unroll
  for (int i = 0; i < 4; ++i){
#pragma unroll
    for (int j = 0; j < JF; ++j){
#pragma unroll
      for (int r = 0; r < 4; ++r){
        int row = rowBase + wm + i * 16 + quad * 4 + r;
        int col = colBase + wn + j * 16 + lm;
        if (row < M && col < N){
          float v = acc[i][j][r] * alpha;
          if (bias) v += bias[col];
          size_t ci = coff + (size_t)row * ldc + col;
          if (resid) v += resid[ci];
          if (act) v = 0.5f * v * (1.f + erff(v * 0.7071067811865476f));
          if (Cf) Cf[ci] = v;
          if (Cb) Cb[ci] = f2b(v);
        }
      }
    }
  }
}

// reduce 4 split-K partial slabs + bias -> tok f32 + bf16 (float4 per thread)
__global__ void kredG1(const float* __restrict__ part, const float* __restrict__ bias,
                       float* __restrict__ tok, short* __restrict__ tokb){
  int idx = blockIdx.x * 256 + threadIdx.x;   // over (4096*512)/4
  const float4* p = (const float4*)part;
  float4 v0 = p[idx], v1 = p[idx + 524288], v2 = p[idx + 1048576], v3 = p[idx + 1572864];
  float4 bv = ((const float4*)bias)[idx & 127];
  float4 v;
  v.x = v0.x + v1.x + v2.x + v3.x + bv.x;
  v.y = v0.y + v1.y + v2.y + v3.y + bv.y;
  v.z = v0.z + v1.z + v2.z + v3.z + bv.z;
  v.w = v0.w + v1.w + v2.w + v3.w + bv.w;
  ((float4*)tok)[idx] = v;
  short4v s4 = { f2b(v.x), f2b(v.y), f2b(v.z), f2b(v.w) };
  *(short4v*)(tokb + (size_t)idx * 4) = s4;
}

// Fused flash attention, split-KV: 1024 blocks = (qt 0..31 of 16 q-rows) x (bh 0..31).
__global__ __launch_bounds__(256) void kflash(const short* __restrict__ qkvb,
                                              const short* __restrict__ Vt,
                                              short* __restrict__ ob){
  __shared__ float Ofs[4][16][128];           // 32 KB; first 2KB of each wave's quarter aliases P
  __shared__ float Ml[4][16], Ll[4][16], Fw[4][16], Linv[16];
  int bid = blockIdx.x;                       // qt*32 + bh (same-bh blocks 32 apart -> same XCD)
  int bh = bid & 31, qt = bid >> 5;
  int b = bh >> 2, h = bh & 3;
  int t = threadIdx.x;
  int w = t >> 6, lane = t & 63;
  int lm = lane & 15, quad = lane >> 4;
  const float SL2 = 0.1275174468f;            // 1/sqrt(128) * log2(e)

  const short* qbase = qkvb + (size_t)(b * 512 + qt * 16 + lm) * 1536 + h * 128 + quad * 8;
  short8 qf[4];
#pragma unroll
  for (int s = 0; s < 4; ++s) qf[s] = *(const short8*)(qbase + s * 32);

  const short* kbase = qkvb + (size_t)(b * 512) * 1536 + 512 + h * 128 + quad * 8;
  const short* vbase = Vt + (size_t)bh * 65536 + (size_t)lm * 512 + quad * 8;

  f32x4 zero4 = {0.f, 0.f, 0.f, 0.f};
  f32x4 Of[8];
#pragma unroll
  for (int i = 0; i < 8; ++i) Of[i] = zero4;
  float mrun[4] = {-1e30f, -1e30f, -1e30f, -1e30f};
  float lrun[4] = {0.f, 0.f, 0.f, 0.f};
  short* Pw = (short*)&Ofs[w][0][0];          // 16x64 bf16 = 2KB, wave-private

#pragma unroll
  for (int kt = 0; kt < 2; ++kt){
    int kb = w * 128 + kt * 64;
    f32x4 Sf[4];
#pragma unroll
    for (int j = 0; j < 4; ++j) Sf[j] = zero4;
#pragma unroll
    for (int s = 0; s < 4; ++s){
#pragma unroll
      for (int j = 0; j < 4; ++j){
        short8 kf = *(const short8*)(kbase + (size_t)(kb + j * 16 + lm) * 1536 + s * 32);
        Sf[j] = __builtin_amdgcn_mfma_f32_16x16x32_bf16(qf[s], kf, Sf[j], 0, 0, 0);
      }
    }
    float alpha[4];
#pragma unroll
    for (int r = 0; r < 4; ++r){
      float mx = fmaxf(fmaxf(Sf[0][r], Sf[1][r]), fmaxf(Sf[2][r], Sf[3][r])) * SL2;
#pragma unroll
      for (int o = 1; o < 16; o <<= 1) mx = fmaxf(mx, __shfl_xor(mx, o));
      float mnew = fmaxf(mrun[r], mx);
      alpha[r] = exp2f(mrun[r] - mnew);
      float psum = 0.f;
#pragma unroll
      for (int j = 0; j < 4; ++j){
        float p = exp2f(Sf[j][r] * SL2 - mnew);
        Sf[j][r] = p;
        psum += p;
      }
#pragma unroll
      for (int o = 1; o < 16; o <<= 1) psum += __shfl_xor(psum, o);
      lrun[r] = lrun[r] * alpha[r] + psum;
      mrun[r] = mnew;
    }
#pragma unroll
    for (int i = 0; i < 8; ++i)
#pragma unroll
      for (int r = 0; r < 4; ++r) Of[i][r] *= alpha[r];
#pragma unroll
    for (int j = 0; j < 4; ++j)
#pragma unroll
      for (int r = 0; r < 4; ++r){
        int q = quad * 4 + r;
        int key = j * 16 + lm;
        Pw[q * 64 + (key ^ ((q & 7) * 8))] = f2b(Sf[j][r]);
      }
#pragma unroll
    for (int ts = 0; ts < 2; ++ts){
      short8 pa = *(const short8*)(Pw + lm * 64 + (((ts * 32 + quad * 8) ^ ((lm & 7) * 8))));
#pragma unroll
      for (int jd = 0; jd < 8; ++jd){
        short8 vf = *(const short8*)(vbase + (size_t)(jd * 16) * 512 + kb + ts * 32);
        Of[jd] = __builtin_amdgcn_mfma_f32_16x16x32_bf16(pa, vf, Of[jd], 0, 0, 0);
      }
    }
  }

#pragma unroll
  for (int jd = 0; jd < 8; ++jd)
#pragma unroll
    for (int r = 0; r < 4; ++r)
      Ofs[w][quad * 4 + r][jd * 16 + lm] = Of[jd][r];
  if (lm == 0){
#pragma unroll
    for (int r = 0; r < 4; ++r){
      Ml[w][quad * 4 + r] = mrun[r];
      Ll[w][quad * 4 + r] = lrun[r];
    }
  }
  __syncthreads();

  if (t < 64){
    int wv = t >> 4, row = t & 15;
    float M = fmaxf(fmaxf(Ml[0][row], Ml[1][row]), fmaxf(Ml[2][row], Ml[3][row]));
    Fw[wv][row] = exp2f(Ml[wv][row] - M);
    if (wv == 0){
      float lsum = Ll[0][row] * exp2f(Ml[0][row] - M) + Ll[1][row] * exp2f(Ml[1][row] - M)
                 + Ll[2][row] * exp2f(Ml[2][row] - M) + Ll[3][row] * exp2f(Ml[3][row] - M);
      Linv[row] = 1.f / lsum;
    }
  }
  __syncthreads();

  {
    int row = t >> 4, dbase = (t & 15) * 8;
    float f0 = Fw[0][row], f1 = Fw[1][row], f2v = Fw[2][row], f3 = Fw[3][row];
    float li = Linv[row];
    short* dst = ob + ((size_t)(b * 512 + qt * 16 + row)) * 512 + h * 128 + dbase;
#pragma unroll
    for (int u = 0; u < 8; ++u){
      float v = Ofs[0][row][dbase + u] * f0 + Ofs[1][row][dbase + u] * f1
              + Ofs[2][row][dbase + u] * f2v + Ofs[3][row][dbase + u] * f3;
      dst[u] = f2b(v * li);
    }
  }
}

// fused: reduce 2 split-K slabs + bias + residual + LayerNorm -> f32 + bf16
// 256-thread blocks, 4 rows per block (one per wave)
__global__ __launch_bounds__(256) void klnR(const float* __restrict__ part,
                     const float* __restrict__ bias,
                     const float* __restrict__ resid,
                     const float* __restrict__ g, const float* __restrict__ bb,
                     float* __restrict__ Yf, short* __restrict__ Yb){
  int row = blockIdx.x * 4 + (threadIdx.x >> 6), lane = threadIdx.x & 63;
  size_t base = (size_t)row * DMODEL;
  float v[8]; float s = 0.f;
#pragma unroll
  for (int i = 0; i < 8; ++i){
    int c = lane + 64 * i;
    v[i] = part[base + c] + part[base + c + 2097152] + bias[c] + resid[base + c];
    s += v[i];
  }
  s = waveSum(s);
  float m = s * (1.f / DMODEL);
  float q = 0.f;
#pragma unroll
  for (int i = 0; i < 8; ++i){ float d = v[i] - m; q += d * d; }
  q = waveSum(q);
  float inv = rsqrtf(q * (1.f / DMODEL) + 1e-5f);
#pragma unroll
  for (int i = 0; i < 8; ++i){
    int c = lane + 64 * i;
    float o = (v[i] - m) * inv * g[c] + bb[c];
    Yf[base + c] = o;
    Yb[base + c] = f2b(o);
  }
}

// fused heads + det-softmax stats: block (b, col) computes all 512 rows' dot(tok_row, w_col)+bias
// on VALU (w_col staged f32 in LDS), writes headS column; det cols also emit max/inv-sum.
__global__ __launch_bounds__(256) void kheadcol(const short* __restrict__ tokb,
                                                const short* __restrict__ Whead,
                                                const float* __restrict__ bhead,
                                                float* __restrict__ headS,
                                                float* __restrict__ dp){
  __shared__ float wf[512];
  __shared__ float redM[4], redS[4];
  int b = blockIdx.x / 60, col = blockIdx.x % 60;
  int t = threadIdx.x;
  // stage w_col as f32
  {
    short2v wv = *(const short2v*)(Whead + col * 512 + t * 2);
    wf[t * 2]     = b2f((unsigned short)wv[0]);
    wf[t * 2 + 1] = b2f((unsigned short)wv[1]);
  }
  __syncthreads();
  float bias = bhead[col];
  float val[2];
#pragma unroll
  for (int rr = 0; rr < 2; ++rr){
    int r = t + rr * 256;
    const short* row = tokb + ((size_t)(b * 512 + r)) * 512;
    float acc = 0.f;
#pragma unroll 8
    for (int k = 0; k < 512; k += 8){
      short8 v = *(const short8*)(row + k);
#pragma unroll
      for (int u = 0; u < 8; ++u) acc += b2f((unsigned short)v[u]) * wf[k + u];
    }
    val[rr] = acc + bias;
    headS[(size_t)(b * 512 + r) * 60 + col] = val[rr];
  }
  if (col >= 30){
    int lane = t & 63, w = t >> 6;
    float mx = fmaxf(val[0], val[1]);
    mx = waveMax(mx);
    if (lane == 0) redM[w] = mx;
    __syncthreads();
    float M = fmaxf(fmaxf(redM[0], redM[1]), fmaxf(redM[2], redM[3]));
    float se = expf(val[0] - M) + expf(val[1] - M);
    se = waveSum(se);
    if (lane == 0) redS[w] = se;
    __syncthreads();
    if (t == 0){
      float S = redS[0] + redS[1] + redS[2] + redS[3];
      dp[b * NCOUT + (col - 30)] = M;
      dp[240 + b * NCOUT + (col - 30)] = 1.f / S;
    }
  }
}

// class softmax + joint + scatter back to original order + ctx copy + video accumulation
// 256-thread blocks, 4 (b,j) per block (one per wave)
__global__ __launch_bounds__(256) void kfinal(const float* __restrict__ hd,
                       const float* __restrict__ dps,
                       const float* __restrict__ tok, const int* __restrict__ sidx,
                       float* __restrict__ out){
  int blk = blockIdx.x * 4 + (threadIdx.x >> 6);
  int b = blk >> 9, j = blk & 511;
  int lane = threadIdx.x & 63;
  int p = sidx[b * PDIM + j];
  float* video = out;
  float* joint = out + 240;
  float* clso  = out + 123120;
  float* deto  = out + 246000;
  float* ctxo  = out + 368880;
  size_t rs60 = (size_t)(b * PDIM + j) * 60;
  size_t ro = (size_t)(b * PDIM + p) * NCOUT;
  float lc = (lane < NCOUT) ? hd[rs60 + lane] : -1e30f;
  float m = waveMax(lc);
  float e = (lane < NCOUT) ? expf(lc - m) : 0.f;
  float s = waveSum(e);
  float cp = e / s;
  if (lane < NCOUT){
    float dv  = hd[rs60 + 30 + lane];
    float dpv = expf(dv - dps[b * NCOUT + lane]) * dps[240 + b * NCOUT + lane];
    float jp  = cp * dpv;
    clso[ro + lane] = lc;
    deto[ro + lane] = dv;
    joint[ro + lane] = jp;
    atomicAdd(&video[b * NCOUT + lane], jp);
  }
  const float4* tr = (const float4*)(tok + (size_t)(b * PDIM + j) * DMODEL);
  float4* cr = (float4*)(ctxo + (size_t)(b * PDIM + p) * DMODEL);
  for (int c = lane; c < DMODEL / 4; c += 64) cr[c] = tr[c];
}

extern "C" void kernel_launch(void* const* d_in, const int* in_sizes, int n_in,
                              void* d_out, int out_size, void* d_ws, size_t ws_size,
                              hipStream_t stream) {
  const float* x      = (const float*)d_in[0];
  const int*   boxes  = (const int*)d_in[1];
  const float* proj_w = (const float*)d_in[2];
  const float* proj_b = (const float*)d_in[3];
  const float* pos_w1 = (const float*)d_in[4];
  const float* pos_b1 = (const float*)d_in[5];
  const float* pos_w2 = (const float*)d_in[6];
  const float* pos_b2 = (const float*)d_in[7];
  const float* qkv_w  = (const float*)d_in[8];
  const float* qkv_b  = (const float*)d_in[9];
  const float* out_w  = (const float*)d_in[10];
  const float* out_b  = (const float*)d_in[11];
  const float* ln1_g  = (const float*)d_in[12];
  const float* ln1_b  = (const float*)d_in[13];
  const float* ff1_w  = (const float*)d_in[14];
  const float* ff1_b  = (const float*)d_in[15];
  const float* ff2_w  = (const float*)d_in[16];
  const float* ff2_b  = (const float*)d_in[17];
  const float* ln2_g  = (const float*)d_in[18];
  const float* ln2_b  = (const float*)d_in[19];
  const float* cls_w  = (const float*)d_in[20];
  const float* cls_b  = (const float*)d_in[21];
  const float* det_w  = (const float*)d_in[22];
  const float* det_b  = (const float*)d_in[23];
  float* out = (float*)d_out;
  float* ws  = (float*)d_ws;

  // ---- workspace layout (FLOAT units) ----
  const size_t oR1    = 0;
  const size_t oS     = 9437184;    // csum (8.39M fl), then G1/out-proj/ff2 partials
  const size_t oOff   = 17825792;   // 131,072 fl (tail of oS region, past csum/partials)
  const size_t oTok   = 22020096;   // 2,097,152 fl
  const size_t oTokb  = 24117248;   // 1,048,576 fl
  const size_t oTok2  = 25165824;   // 2,097,152 fl
  const size_t oTok2b = 27262976;   // 1,048,576 fl
  const size_t oWcat  = 28311552;   // 1,048,576 fl
  const size_t oBcat  = 29360128;   // 512 fl
  const size_t oWq    = 29360640;   // k0 prep dest base; contiguous qkv|out|ff1|ff2|cls|det
  const size_t oWo    = 30147072;
  const size_t oWf1   = 30409216;
  const size_t oWf2   = 30933504;
  const size_t oWcls  = 31457792;
  const size_t oTot   = 31473152;   // 131,072 fl (32 chunks)
  const size_t oBhead = 31604224;   // 576 fl
  const size_t oSidx  = 31608320;   // int[4096]

  short* Abf   = (short*)(ws + oR1);
  short* qkvb  = (short*)(ws + oR1);
  short* Vt    = (short*)(ws + oR1 + 3145728);
  short* obufb = (short*)(ws + oR1 + 4194304);
  short* hbufb = (short*)(ws + oR1 + 5242880);
  float* headS = ws + oR1 + 7340032;              // [4096][60] after layers (hbufb dead)
  float* dpS   = ws + oR1 + 7585792;
  float* csum  = ws + oS;
  float* Cpart = ws + oS;
  float* Cp2   = ws + oS;                          // 2-slab partials (out-proj / ff2)
  float* offp  = ws + oOff;
  float* tok   = ws + oTok;
  short* tokb  = (short*)(ws + oTokb);
  float* tok2  = ws + oTok2;
  short* tok2b = (short*)(ws + oTok2b);
  short* Wcatb = (short*)(ws + oWcat);
  float* bcat  = ws + oBcat;
  short* Wq    = (short*)(ws + oWq);
  short* Wo    = (short*)(ws + oWo);
  short* Wf1   = (short*)(ws + oWf1);
  short* Wf2   = (short*)(ws + oWf2);
  short* Whead = (short*)(ws + oWcls);            // cls||det rows: [60][512]
  float* tot   = ws + oTot;
  float* bhead = ws + oBhead;
  int*   sidx  = (int*)(ws + oSidx);

  // merged scan | sort | weight-prep (256 + 8 + 3088 blocks, 512 threads; prep vectorized x4)
  k0<<<3352, 512, 0, stream>>>(x, boxes, proj_w, pos_w2, qkv_w, out_w, ff1_w, ff2_w,
                               cls_w, det_w, proj_b, pos_b2, cls_b, det_b,
                               csum, tot, sidx, out, Wcatb, Wq, bcat, bhead);
  koff<<<16, 256, 0, stream>>>(tot, offp);
  // SPP pooling (zero-LDS, dedup'd rows, uniform reciprocals)
  kspp<<<BDIM * PDIM, 256, 0, stream>>>(csum, offp, boxes, sidx, pos_w1, pos_b1, Abf);

  // G1 split-K-4 x BN=64, XCD-swizzled: 1024 blocks (4/CU)
  gemm_bt<64, 1><<<dim3(8, 32, 4), 256, 0, stream>>>(
      4096, 512, 1024, Abf, 4096, 1024, 0, Wcatb, 4096, 1024, 0,
      Cpart, nullptr, 512, 2097152, 0, 1, 1.f, nullptr, nullptr, 0, nullptr);
  kredG1<<<2048, 256, 0, stream>>>(Cpart, bcat, tok, tokb);

  for (int l = 0; l < 2; ++l){
    const short* qw  = Wq  + (size_t)l * 1536 * 512;
    const short* ow  = Wo  + (size_t)l * 512 * 512;
    const short* f1w = Wf1 + (size_t)l * 1024 * 512;
    const short* f2w = Wf2 + (size_t)l * 512 * 1024;
    const float* qb  = qkv_b + (size_t)l * 1536;
    const float* obv = out_b + (size_t)l * 512;
    const float* f1b = ff1_b + (size_t)l * 1024;
    const float* f2b_ = ff2_b + (size_t)l * 512;

    // qkv = tok @ qkv_w^T + qkv_b   [4096, 1536] (bf16; 768 blocks, 3/CU)
    // V-columns blocks (bx>=16) write transposed directly into Vt (kvt fused away)
    gemm_bt<64><<<dim3(24, 32, 1), 256, 0, stream>>>(
        4096, 1536, 512, tokb, 512, 0, 0, qw, 512, 0, 0,
        nullptr, qkvb, 1536, 0, 0, 1, 1.f, qb, nullptr, 0, Vt);
    // fused flash attention (split-KV, 1024 blocks) -> obufb[b][q][h*128+d]
    kflash<<<1024, 256, 0, stream>>>(qkvb, Vt, obufb);
    // out-proj split-K-2 (512 blocks), then fused reduce+bias+resid+LN1
    gemm_bt<64><<<dim3(8, 32, 2), 256, 0, stream>>>(
        4096, 512, 256, obufb, 512, 256, 0, ow, 512, 256, 0,
        Cp2, nullptr, 512, 2097152, 0, 1, 1.f, nullptr, nullptr, 0, nullptr);
    klnR<<<1024, 256, 0, stream>>>(Cp2, obv, tok, ln1_g + l * 512, ln1_b + l * 512, tok2, tok2b);
    // hbuf = gelu(tok2 @ ff1^T + b1) (bf16; 512 blocks)
    gemm_bt<64><<<dim3(16, 32, 1), 256, 0, stream>>>(
        4096, 1024, 512, tok2b, 512, 0, 0, f1w, 512, 0, 0,
        nullptr, hbufb, 1024, 0, 0, 1, 1.f, f1b, nullptr, 1, nullptr);
    // ff2 split-K-2 (512 blocks), then fused reduce+bias+resid+LN2
    gemm_bt<64><<<dim3(8, 32, 2), 256, 0, stream>>>(
        4096, 512, 512, hbufb, 1024, 512, 0, f2w, 1024, 512, 0,
        Cp2, nullptr, 512, 2097152, 0, 1, 1.f, nullptr, nullptr, 0, nullptr);
    klnR<<<1024, 256, 0, stream>>>(Cp2, f2b_, tok2, ln2_g + l * 512, ln2_b + l * 512, tok, tokb);
  }

  // fused heads + det stats: 480 blocks = (b, col)
  kheadcol<<<480, 256, 0, stream>>>(tokb, Whead, bhead, headS, dpS);
  kfinal<<<1024, 256, 0, stream>>>(headS, dpS, tok, sidx, out);
}

// Round 11
// 477.109 us; speedup vs baseline: 1.0569x; 1.0569x over previous
//
#include <hip/hip_runtime.h>

#define TDIM 2048
#define CDIM 512
#define BDIM 8
#define PDIM 512
#define DMODEL 512
#define NCOUT 30
#define SPPOUT 3584
#define AKDIM 4096   // SPPOUT + DMODEL

typedef __attribute__((ext_vector_type(8))) short short8;
typedef __attribute__((ext_vector_type(4))) short short4v;
typedef __attribute__((ext_vector_type(2))) short short2v;
typedef __attribute__((ext_vector_type(4))) float f32x4;

typedef const __attribute__((address_space(1))) void* as1cv;
typedef __attribute__((address_space(3))) void* as3v;

// async global->LDS, 16B per lane; LDS dest must be wave-uniform base + lane*16
__device__ __forceinline__ void gl_lds16(const short* g, short* l){
  __builtin_amdgcn_global_load_lds((as1cv)g, (as3v)l, 16, 0, 0);
}

__device__ __forceinline__ short f2b(float f){
  unsigned u = __float_as_uint(f);
  unsigned r = (u + 0x7fffu + ((u >> 16) & 1u)) >> 16;
  return (short)r;
}

__device__ __forceinline__ float waveSum(float v){
#pragma unroll
  for (int o = 32; o > 0; o >>= 1) v += __shfl_xor(v, o);
  return v;
}
__device__ __forceinline__ float waveMax(float v){
#pragma unroll
  for (int o = 32; o > 0; o >>= 1) v = fmaxf(v, __shfl_xor(v, o));
  return v;
}

// ---- merged front kernel: blocks [0,256) scan | [256,264) sort | [264,..) weight prep ----
// scan: 32 chunks of 64 along T (1 block/CU): csum[b][t][c], tot[b][ch][c]
// prep: float4/short4 vectorized (all section boundaries 4-aligned)
__global__ __launch_bounds__(512) void k0(
    const float* __restrict__ x, const int* __restrict__ boxes,
    const float* __restrict__ pw, const float* __restrict__ pw2,
    const float* __restrict__ qw, const float* __restrict__ ow,
    const float* __restrict__ f1, const float* __restrict__ f2,
    const float* __restrict__ cl, const float* __restrict__ dt,
    const float* __restrict__ pb, const float* __restrict__ pb2,
    const float* __restrict__ cb, const float* __restrict__ db,
    float* __restrict__ W, float* __restrict__ tot,
    int* __restrict__ sidx, float* __restrict__ out,
    short* __restrict__ Wc, short* __restrict__ Wd,
    float* __restrict__ bc, float* __restrict__ bh)
{
  __shared__ unsigned key[PDIM];
  int blk = blockIdx.x, t = threadIdx.x;
  if (blk < 256){
    int b = blk >> 5, ch = blk & 31;
    int c = t;
    const float* xp = x + ((size_t)(b * CDIM + c)) * TDIM + ch * 64;
    float* wp = W + ((size_t)b * TDIM + ch * 64) * CDIM + c;
    float run = 0.f;
    for (int tl = 0; tl < 64; tl += 4){
      float4 v = *(const float4*)(xp + tl);
      run += v.x; wp[(size_t)(tl + 0) * CDIM] = run;
      run += v.y; wp[(size_t)(tl + 1) * CDIM] = run;
      run += v.z; wp[(size_t)(tl + 2) * CDIM] = run;
      run += v.w; wp[(size_t)(tl + 3) * CDIM] = run;
    }
    tot[((size_t)b * 32 + ch) * CDIM + c] = run;
  } else if (blk < 264){
    int b = blk - 256;
    if (b == 0 && t < 240) out[t] = 0.f;
    int s = boxes[(size_t)(b * PDIM + t) * 2];
    int e = boxes[(size_t)(b * PDIM + t) * 2 + 1];
    key[t] = ((unsigned)(s + e) << 9) | (unsigned)t;
    __syncthreads();
    for (int k = 2; k <= PDIM; k <<= 1){
      for (int j = k >> 1; j > 0; j >>= 1){
        int ixj = t ^ j;
        if (ixj > t){
          unsigned a = key[t], c2 = key[ixj];
          bool up = ((t & k) == 0);
          bool doswap = up ? (a > c2) : (a < c2);
          if (doswap){ key[t] = c2; key[ixj] = a; }
        }
        __syncthreads();
      }
    }
    sidx[b * PDIM + t] = (int)(key[t] & 511u);
  } else {
    int i4 = (blk - 264) * 512 + t;
    if (i4 < 524288){                       // Wc: elements [0, 2097152), 4 per slot
      int base = i4 * 4;
      int r = base >> 12, k = base & 4095;
      float4 v;
      if (k < SPPOUT) v = *(const float4*)(pw + (size_t)r * SPPOUT + k);
      else            v = *(const float4*)(pw2 + (size_t)r * DMODEL + (k - SPPOUT));
      short4v s = { f2b(v.x), f2b(v.y), f2b(v.z), f2b(v.w) };
      *(short4v*)(Wc + base) = s;
    } else if (i4 < 1580544){               // Wd: j in [0, 4225024), 4 per slot
      int j = i4 * 4 - 2097152;
      const float* src; int off;
      if (j < 1572864){ src = qw; off = j; }
      else if (j < 2097152){ src = ow; off = j - 1572864; }
      else if (j < 3145728){ src = f1; off = j - 2097152; }
      else if (j < 4194304){ src = f2; off = j - 3145728; }
      else if (j < 4209664){ src = cl; off = j - 4194304; }
      else { src = dt; off = j - 4209664; }
      float4 v = *(const float4*)(src + off);
      short4v s = { f2b(v.x), f2b(v.y), f2b(v.z), f2b(v.w) };
      *(short4v*)(Wd + j) = s;
    } else if (i4 < 1580688){               // biases: k in [0,576)
      int k = (i4 - 1580544) * 4;
#pragma unroll
      for (int u = 0; u < 4; ++u){
        int kk = k + u;
        if (kk < 512) bc[kk] = pb[kk] + pb2[kk];
        else if (kk < 572) bh[kk - 512] = (kk < 542) ? cb[kk - 512] : db[kk - 542];
      }
    }
  }
}

// exclusive prefix of per-chunk totals -> off[b][ch][c], 32 chunks
__global__ void koff(const float* __restrict__ tot, float* __restrict__ off){
  int b = blockIdx.x >> 1, cg = blockIdx.x & 1;
  int c = cg * 256 + threadIdx.x;
  float run = 0.f;
  for (int ch = 0; ch < 32; ++ch){
    off[((size_t)b * 32 + ch) * CDIM + c] = run;
    run += tot[((size_t)b * 32 + ch) * CDIM + c];
  }
}

// SPP pooling + pos-MLP hidden, staged in sorted order as bf16: A[b][j][0..4095]
// Zero LDS (max occupancy); 10 dedup'd prefix rows; uniform reciprocals.
__global__ void kspp(const float* __restrict__ W, const float* __restrict__ off,
                     const int* __restrict__ boxes, const int* __restrict__ sidx,
                     const float* __restrict__ pw1, const float* __restrict__ pb1,
                     short* __restrict__ A){
  int blk = blockIdx.x;
  int b = blk >> 9, j = blk & 511;
  int p = sidx[b * PDIM + j];
  int s0 = boxes[(size_t)(b * PDIM + p) * 2];
  int e0 = boxes[(size_t)(b * PDIM + p) * 2 + 1];
  int start = min(max(s0, 0), TDIM - 1);
  int end   = min(max(e0, 1), TDIM);
  if (end <= start) end = min(start + 1, TDIM);
  int n = end - start;

  int lo[7], hi[7];
  {
    const int Ls[3] = {1, 2, 4};
    int q = 0;
    for (int li = 0; li < 3; ++li){
      int L = Ls[li];
      for (int i = 0; i < L; ++i){
        lo[q] = start + (i * n) / L;
        hi[q] = start + ((i + 1) * n + L - 1) / L;
        ++q;
      }
    }
  }
  float inv[7];
#pragma unroll
  for (int q = 0; q < 7; ++q) inv[q] = 1.f / (float)(hi[q] - lo[q]);

  // 10 distinct prefix rows; F(-1) = 0. (F(start-1) used 3x, F(end-1) used 3x)
  int R[10] = { start - 1, end - 1, hi[1] - 1, lo[2] - 1, hi[3] - 1,
                lo[4] - 1, hi[4] - 1, lo[5] - 1, hi[5] - 1, lo[6] - 1 };

  float s_f = (float)s0, e_f = (float)e0;
  float px = (s_f + e_f) * 0.5f / (float)TDIM;
  float py = fmaxf(e_f - s_f, 1.f) / (float)TDIM;
  short* Ar = A + (size_t)(b * PDIM + j) * AKDIM;
  const float* Wb = W + (size_t)b * TDIM * CDIM;
  const float* ob = off + (size_t)b * 32 * CDIM;
#pragma unroll
  for (int cc = 0; cc < 2; ++cc){
    int c = threadIdx.x + cc * 256;
    float F[10];
#pragma unroll
    for (int u = 0; u < 10; ++u){
      int r = R[u];
      F[u] = (r < 0) ? 0.f : (Wb[(size_t)r * CDIM + c] + ob[(r >> 6) * CDIM + c]);
    }
    Ar[c]              = f2b((F[1] - F[0]) * inv[0]);
    Ar[512  + c * 2]   = f2b((F[2] - F[0]) * inv[1]);
    Ar[513  + c * 2]   = f2b((F[1] - F[3]) * inv[2]);
    Ar[1536 + c * 4]   = f2b((F[4] - F[0]) * inv[3]);
    Ar[1537 + c * 4]   = f2b((F[6] - F[5]) * inv[4]);
    Ar[1538 + c * 4]   = f2b((F[8] - F[7]) * inv[5]);
    Ar[1539 + c * 4]   = f2b((F[1] - F[9]) * inv[6]);
    float hv = pw1[c * 2] * px + pw1[c * 2 + 1] * py + pb1[c];
    Ar[SPPOUT + c] = f2b(fmaxf(hv, 0.f));
  }
}

// MFMA bf16 GEMM (nt): C[M,N] = act(alpha * A[M,K] @ B[N,K]^T + bias + resid)
// 128-row tiles, BK=64, XOR-swizzled LDS (conflict-free frag reads).
// SWZ=1: XCD-locality remap (row-chunked, bijective); requires gridDim.y % 8 == 0.
// Vtp: if set and colBase>=1024 (qkv call), the block's output is the V part ->
//      transpose via LDS and store coalesced into Vt[b*4+h][128][512] (skips Cb write).
template<int BN, int SWZ = 0>
__global__ __launch_bounds__(256) void gemm_bt(
    int M, int N, int K,
    const short* __restrict__ A, int lda, long long sAb, long long sAh,
    const short* __restrict__ B, int ldb, long long sBb, long long sBh,
    float* __restrict__ Cf, short* __restrict__ Cb, int ldc, long long sCb, long long sCh,
    int hdiv, float alpha,
    const float* __restrict__ bias, const float* __restrict__ resid, int act,
    short* __restrict__ Vtp)
{
  constexpr int JF = BN / 32;                 // B-frags per wave / B staging batches
  __shared__ short smem[128 * 64 + BN * 64];
  short* As = smem;
  short* Bs = smem + 128 * 64;
  int bx = blockIdx.x, by = blockIdx.y, bz = blockIdx.z;
  if constexpr (SWZ){
    // each XCD owns ny/8 consecutive row-strips across all bx,bz (A-slab L2 reuse)
    int nx = gridDim.x, ny = gridDim.y;
    int rt = ny >> 3;
    int flat = (bz * ny + by) * nx + bx;
    int xcd = flat & 7, wl = flat >> 3;
    by = xcd * rt + wl % rt;
    int rest = wl / rt;
    bx = rest % nx;
    bz = rest / nx;
  }
  int zb = bz / hdiv, zh = bz - zb * hdiv;
  A += (size_t)zb * sAb + (size_t)zh * sAh;
  B += (size_t)zb * sBb + (size_t)zh * sBh;
  size_t coff = (size_t)zb * sCb + (size_t)zh * sCh;
  int rowBase = by * 128, colBase = bx * BN;
  int t = threadIdx.x;
  int lane = t & 63;
  int wave = t >> 6;
  int wm = (wave >> 1) * 64, wn = (wave & 1) * (BN / 2);
  int lm = lane & 15, quad = lane >> 4;
  int srow = t >> 3;
  int skw = ((t & 7) * 8) ^ ((srow & 7) * 8);

  const short* Agp[4];
#pragma unroll
  for (int it = 0; it < 4; ++it)
    Agp[it] = A + (size_t)min(rowBase + srow + it * 32, M - 1) * lda + skw;
  const short* Bgp[JF];
#pragma unroll
  for (int it = 0; it < JF; ++it)
    Bgp[it] = B + (size_t)min(colBase + srow + it * 32, N - 1) * ldb + skw;

  f32x4 zero4 = {0.f, 0.f, 0.f, 0.f};
  f32x4 acc[4][JF];
#pragma unroll
  for (int i = 0; i < 4; ++i)
#pragma unroll
    for (int j = 0; j < JF; ++j) acc[i][j] = zero4;

  int axr = (lm & 7) * 8;
  for (int k0 = 0; k0 < K; k0 += 64){
#pragma unroll
    for (int it = 0; it < 4; ++it) gl_lds16(Agp[it] + k0, As + it * 2048 + t * 8);
#pragma unroll
    for (int it = 0; it < JF; ++it) gl_lds16(Bgp[it] + k0, Bs + it * 2048 + t * 8);
    __syncthreads();
#pragma unroll
    for (int h = 0; h < 2; ++h){
      int koff = (h * 32 + quad * 8) ^ axr;
      short8 af[4], bfr[JF];
#pragma unroll
      for (int i = 0; i < 4; ++i)
        af[i] = *(const short8*)(As + (wm + i * 16 + lm) * 64 + koff);
#pragma unroll
      for (int j = 0; j < JF; ++j)
        bfr[j] = *(const short8*)(Bs + (wn + j * 16 + lm) * 64 + koff);
#pragma unroll
      for (int i = 0; i < 4; ++i)
#pragma unroll
        for (int j = 0; j < JF; ++j)
          acc[i][j] = __builtin_amdgcn_mfma_f32_16x16x32_bf16(af[i], bfr[j], acc[i][j], 0, 0, 0);
    }
    __syncthreads();
  }

  if (Vtp && colBase >= 1024){
    // whole-block V output: bf16-transpose in LDS (pitch 132 kills bank conflicts),
    // then coalesced 64B-per-thread stores into Vt[b*4+h][d][p].
    short* LT = smem;
#pragma unroll
    for (int i = 0; i < 4; ++i){
#pragma unroll
      for (int j = 0; j < JF; ++j){
        int d = wn + j * 16 + lm;
        int prow = wm + i * 16 + quad * 4;
        short4v pk;
#pragma unroll
        for (int r = 0; r < 4; ++r){
          float v = acc[i][j][r] * alpha;
          if (bias) v += bias[colBase + d];
          pk[r] = f2b(v);
        }
        *(short4v*)(LT + d * 132 + prow) = pk;
      }
    }
    __syncthreads();
    int bb = rowBase >> 9;
    int hh = (colBase - 1024) >> 7;
    int dd0 = (colBase - 1024) & 127;
    int dl = t >> 2, pl = (t & 3) * 32;
    const short* sp = LT + dl * 132 + pl;
    short* dp = Vtp + ((size_t)(bb * 4 + hh)) * 65536 + (size_t)(dd0 + dl) * 512 + (rowBase & 511) + pl;
#pragma unroll
    for (int u = 0; u < 4; ++u) *(short8*)(dp + u * 8) = *(const short8*)(sp + u * 8);
    return;
  }

#pragma unroll
  for (int i = 0; i < 4; ++i){
#pragma unroll
    for (int j = 0; j < JF; ++j){
#pragma unroll
      for (int r = 0; r < 4; ++r){
        int row = rowBase + wm + i * 16 + quad * 4 + r;
        int col = colBase + wn + j * 16 + lm;
        if (row < M && col < N){
          float v = acc[i][j][r] * alpha;
          if (bias) v += bias[col];
          size_t ci = coff + (size_t)row * ldc + col;
          if (resid) v += resid[ci];
          if (act) v = 0.5f * v * (1.f + erff(v * 0.7071067811865476f));
          if (Cf) Cf[ci] = v;
          if (Cb) Cb[ci] = f2b(v);
        }
      }
    }
  }
}

// reduce 4 split-K partial slabs + bias -> tok f32 + bf16 (float4 per thread)
__global__ void kredG1(const float* __restrict__ part, const float* __restrict__ bias,
                       float* __restrict__ tok, short* __restrict__ tokb){
  int idx = blockIdx.x * 256 + threadIdx.x;   // over (4096*512)/4
  const float4* p = (const float4*)part;
  float4 v0 = p[idx], v1 = p[idx + 524288], v2 = p[idx + 1048576], v3 = p[idx + 1572864];
  float4 bv = ((const float4*)bias)[idx & 127];
  float4 v;
  v.x = v0.x + v1.x + v2.x + v3.x + bv.x;
  v.y = v0.y + v1.y + v2.y + v3.y + bv.y;
  v.z = v0.z + v1.z + v2.z + v3.z + bv.z;
  v.w = v0.w + v1.w + v2.w + v3.w + bv.w;
  ((float4*)tok)[idx] = v;
  short4v s4 = { f2b(v.x), f2b(v.y), f2b(v.z), f2b(v.w) };
  *(short4v*)(tokb + (size_t)idx * 4) = s4;
}

// Fused flash attention, split-KV: 1024 blocks = (qt 0..31 of 16 q-rows) x (bh 0..31).
__global__ __launch_bounds__(256) void kflash(const short* __restrict__ qkvb,
                                              const short* __restrict__ Vt,
                                              short* __restrict__ ob){
  __shared__ float Ofs[4][16][128];           // 32 KB; first 2KB of each wave's quarter aliases P
  __shared__ float Ml[4][16], Ll[4][16], Fw[4][16], Linv[16];
  int bid = blockIdx.x;                       // qt*32 + bh (same-bh blocks 32 apart -> same XCD)
  int bh = bid & 31, qt = bid >> 5;
  int b = bh >> 2, h = bh & 3;
  int t = threadIdx.x;
  int w = t >> 6, lane = t & 63;
  int lm = lane & 15, quad = lane >> 4;
  const float SL2 = 0.1275174468f;            // 1/sqrt(128) * log2(e)

  const short* qbase = qkvb + (size_t)(b * 512 + qt * 16 + lm) * 1536 + h * 128 + quad * 8;
  short8 qf[4];
#pragma unroll
  for (int s = 0; s < 4; ++s) qf[s] = *(const short8*)(qbase + s * 32);

  const short* kbase = qkvb + (size_t)(b * 512) * 1536 + 512 + h * 128 + quad * 8;
  const short* vbase = Vt + (size_t)bh * 65536 + (size_t)lm * 512 + quad * 8;

  f32x4 zero4 = {0.f, 0.f, 0.f, 0.f};
  f32x4 Of[8];
#pragma unroll
  for (int i = 0; i < 8; ++i) Of[i] = zero4;
  float mrun[4] = {-1e30f, -1e30f, -1e30f, -1e30f};
  float lrun[4] = {0.f, 0.f, 0.f, 0.f};
  short* Pw = (short*)&Ofs[w][0][0];          // 16x64 bf16 = 2KB, wave-private

#pragma unroll
  for (int kt = 0; kt < 2; ++kt){
    int kb = w * 128 + kt * 64;
    f32x4 Sf[4];
#pragma unroll
    for (int j = 0; j < 4; ++j) Sf[j] = zero4;
#pragma unroll
    for (int s = 0; s < 4; ++s){
#pragma unroll
      for (int j = 0; j < 4; ++j){
        short8 kf = *(const short8*)(kbase + (size_t)(kb + j * 16 + lm) * 1536 + s * 32);
        Sf[j] = __builtin_amdgcn_mfma_f32_16x16x32_bf16(qf[s], kf, Sf[j], 0, 0, 0);
      }
    }
    float alpha[4];
#pragma unroll
    for (int r = 0; r < 4; ++r){
      float mx = fmaxf(fmaxf(Sf[0][r], Sf[1][r]), fmaxf(Sf[2][r], Sf[3][r])) * SL2;
#pragma unroll
      for (int o = 1; o < 16; o <<= 1) mx = fmaxf(mx, __shfl_xor(mx, o));
      float mnew = fmaxf(mrun[r], mx);
      alpha[r] = exp2f(mrun[r] - mnew);
      float psum = 0.f;
#pragma unroll
      for (int j = 0; j < 4; ++j){
        float p = exp2f(Sf[j][r] * SL2 - mnew);
        Sf[j][r] = p;
        psum += p;
      }
#pragma unroll
      for (int o = 1; o < 16; o <<= 1) psum += __shfl_xor(psum, o);
      lrun[r] = lrun[r] * alpha[r] + psum;
      mrun[r] = mnew;
    }
#pragma unroll
    for (int i = 0; i < 8; ++i)
#pragma unroll
      for (int r = 0; r < 4; ++r) Of[i][r] *= alpha[r];
#pragma unroll
    for (int j = 0; j < 4; ++j)
#pragma unroll
      for (int r = 0; r < 4; ++r){
        int q = quad * 4 + r;
        int key = j * 16 + lm;
        Pw[q * 64 + (key ^ ((q & 7) * 8))] = f2b(Sf[j][r]);
      }
#pragma unroll
    for (int ts = 0; ts < 2; ++ts){
      short8 pa = *(const short8*)(Pw + lm * 64 + (((ts * 32 + quad * 8) ^ ((lm & 7) * 8))));
#pragma unroll
      for (int jd = 0; jd < 8; ++jd){
        short8 vf = *(const short8*)(vbase + (size_t)(jd * 16) * 512 + kb + ts * 32);
        Of[jd] = __builtin_amdgcn_mfma_f32_16x16x32_bf16(pa, vf, Of[jd], 0, 0, 0);
      }
    }
  }

#pragma unroll
  for (int jd = 0; jd < 8; ++jd)
#pragma unroll
    for (int r = 0; r < 4; ++r)
      Ofs[w][quad * 4 + r][jd * 16 + lm] = Of[jd][r];
  if (lm == 0){
#pragma unroll
    for (int r = 0; r < 4; ++r){
      Ml[w][quad * 4 + r] = mrun[r];
      Ll[w][quad * 4 + r] = lrun[r];
    }
  }
  __syncthreads();

  if (t < 64){
    int wv = t >> 4, row = t & 15;
    float M = fmaxf(fmaxf(Ml[0][row], Ml[1][row]), fmaxf(Ml[2][row], Ml[3][row]));
    Fw[wv][row] = exp2f(Ml[wv][row] - M);
    if (wv == 0){
      float lsum = Ll[0][row] * exp2f(Ml[0][row] - M) + Ll[1][row] * exp2f(Ml[1][row] - M)
                 + Ll[2][row] * exp2f(Ml[2][row] - M) + Ll[3][row] * exp2f(Ml[3][row] - M);
      Linv[row] = 1.f / lsum;
    }
  }
  __syncthreads();

  {
    int row = t >> 4, dbase = (t & 15) * 8;
    float f0 = Fw[0][row], f1 = Fw[1][row], f2v = Fw[2][row], f3 = Fw[3][row];
    float li = Linv[row];
    short* dst = ob + ((size_t)(b * 512 + qt * 16 + row)) * 512 + h * 128 + dbase;
#pragma unroll
    for (int u = 0; u < 8; ++u){
      float v = Ofs[0][row][dbase + u] * f0 + Ofs[1][row][dbase + u] * f1
              + Ofs[2][row][dbase + u] * f2v + Ofs[3][row][dbase + u] * f3;
      dst[u] = f2b(v * li);
    }
  }
}

// fused: reduce 2 split-K slabs + bias + residual + LayerNorm -> f32 + bf16
// 256-thread blocks, 4 rows per block (one per wave)
__global__ __launch_bounds__(256) void klnR(const float* __restrict__ part,
                     const float* __restrict__ bias,
                     const float* __restrict__ resid,
                     const float* __restrict__ g, const float* __restrict__ bb,
                     float* __restrict__ Yf, short* __restrict__ Yb){
  int row = blockIdx.x * 4 + (threadIdx.x >> 6), lane = threadIdx.x & 63;
  size_t base = (size_t)row * DMODEL;
  float v[8]; float s = 0.f;
#pragma unroll
  for (int i = 0; i < 8; ++i){
    int c = lane + 64 * i;
    v[i] = part[base + c] + part[base + c + 2097152] + bias[c] + resid[base + c];
    s += v[i];
  }
  s = waveSum(s);
  float m = s * (1.f / DMODEL);
  float q = 0.f;
#pragma unroll
  for (int i = 0; i < 8; ++i){ float d = v[i] - m; q += d * d; }
  q = waveSum(q);
  float inv = rsqrtf(q * (1.f / DMODEL) + 1e-5f);
#pragma unroll
  for (int i = 0; i < 8; ++i){
    int c = lane + 64 * i;
    float o = (v[i] - m) * inv * g[c] + bb[c];
    Yf[base + c] = o;
    Yb[base + c] = f2b(o);
  }
}

// det softmax stats over P (columns) of headS [4096][60] det part ->
// per-(b,c) max and inverse-sum (kfinal reconstructs the softmax value inline)
__global__ void kdetsm(const float* __restrict__ hd, float* __restrict__ dp){
  int b = blockIdx.x / NCOUT, c = blockIdx.x % NCOUT, lane = threadIdx.x;
  float v[8]; float m = -1e30f;
#pragma unroll
  for (int i = 0; i < 8; ++i){
    v[i] = hd[((size_t)(b * PDIM) + lane + 64 * i) * 60 + 30 + c];
    m = fmaxf(m, v[i]);
  }
  m = waveMax(m);
  float s = 0.f;
#pragma unroll
  for (int i = 0; i < 8; ++i){ s += expf(v[i] - m); }
  s = waveSum(s);
  if (lane == 0){
    dp[b * NCOUT + c] = m;
    dp[240 + b * NCOUT + c] = 1.f / s;
  }
}

// class softmax + joint + scatter back to original order + ctx copy + video accumulation
// 256-thread blocks, 4 (b,j) per block (one per wave)
__global__ __launch_bounds__(256) void kfinal(const float* __restrict__ hd,
                       const float* __restrict__ dps,
                       const float* __restrict__ tok, const int* __restrict__ sidx,
                       float* __restrict__ out){
  int blk = blockIdx.x * 4 + (threadIdx.x >> 6);
  int b = blk >> 9, j = blk & 511;
  int lane = threadIdx.x & 63;
  int p = sidx[b * PDIM + j];
  float* video = out;
  float* joint = out + 240;
  float* clso  = out + 123120;
  float* deto  = out + 246000;
  float* ctxo  = out + 368880;
  size_t rs60 = (size_t)(b * PDIM + j) * 60;
  size_t ro = (size_t)(b * PDIM + p) * NCOUT;
  float lc = (lane < NCOUT) ? hd[rs60 + lane] : -1e30f;
  float m = waveMax(lc);
  float e = (lane < NCOUT) ? expf(lc - m) : 0.f;
  float s = waveSum(e);
  float cp = e / s;
  if (lane < NCOUT){
    float dv  = hd[rs60 + 30 + lane];
    float dpv = expf(dv - dps[b * NCOUT + lane]) * dps[240 + b * NCOUT + lane];
    float jp  = cp * dpv;
    clso[ro + lane] = lc;
    deto[ro + lane] = dv;
    joint[ro + lane] = jp;
    atomicAdd(&video[b * NCOUT + lane], jp);
  }
  const float4* tr = (const float4*)(tok + (size_t)(b * PDIM + j) * DMODEL);
  float4* cr = (float4*)(ctxo + (size_t)(b * PDIM + p) * DMODEL);
  for (int c = lane; c < DMODEL / 4; c += 64) cr[c] = tr[c];
}

extern "C" void kernel_launch(void* const* d_in, const int* in_sizes, int n_in,
                              void* d_out, int out_size, void* d_ws, size_t ws_size,
                              hipStream_t stream) {
  const float* x      = (const float*)d_in[0];
  const int*   boxes  = (const int*)d_in[1];
  const float* proj_w = (const float*)d_in[2];
  const float* proj_b = (const float*)d_in[3];
  const float* pos_w1 = (const float*)d_in[4];
  const float* pos_b1 = (const float*)d_in[5];
  const float* pos_w2 = (const float*)d_in[6];
  const float* pos_b2 = (const float*)d_in[7];
  const float* qkv_w  = (const float*)d_in[8];
  const float* qkv_b  = (const float*)d_in[9];
  const float* out_w  = (const float*)d_in[10];
  const float* out_b  = (const float*)d_in[11];
  const float* ln1_g  = (const float*)d_in[12];
  const float* ln1_b  = (const float*)d_in[13];
  const float* ff1_w  = (const float*)d_in[14];
  const float* ff1_b  = (const float*)d_in[15];
  const float* ff2_w  = (const float*)d_in[16];
  const float* ff2_b  = (const float*)d_in[17];
  const float* ln2_g  = (const float*)d_in[18];
  const float* ln2_b  = (const float*)d_in[19];
  const float* cls_w  = (const float*)d_in[20];
  const float* cls_b  = (const float*)d_in[21];
  const float* det_w  = (const float*)d_in[22];
  const float* det_b  = (const float*)d_in[23];
  float* out = (float*)d_out;
  float* ws  = (float*)d_ws;

  // ---- workspace layout (FLOAT units) ----
  const size_t oR1    = 0;
  const size_t oS     = 9437184;    // csum (8.39M fl), then G1/out-proj/ff2 partials
  const size_t oOff   = 17825792;   // 131,072 fl (tail of oS region, past csum/partials)
  const size_t oTok   = 22020096;   // 2,097,152 fl
  const size_t oTokb  = 24117248;   // 1,048,576 fl
  const size_t oTok2  = 25165824;   // 2,097,152 fl
  const size_t oTok2b = 27262976;   // 1,048,576 fl
  const size_t oWcat  = 28311552;   // 1,048,576 fl
  const size_t oBcat  = 29360128;   // 512 fl
  const size_t oWq    = 29360640;   // k0 prep dest base; contiguous qkv|out|ff1|ff2|cls|det
  const size_t oWo    = 30147072;
  const size_t oWf1   = 30409216;
  const size_t oWf2   = 30933504;
  const size_t oWcls  = 31457792;
  const size_t oTot   = 31473152;   // 131,072 fl (32 chunks)
  const size_t oBhead = 31604224;   // 576 fl
  const size_t oSidx  = 31608320;   // int[4096]

  short* Abf   = (short*)(ws + oR1);
  short* qkvb  = (short*)(ws + oR1);
  short* Vt    = (short*)(ws + oR1 + 3145728);
  short* obufb = (short*)(ws + oR1 + 4194304);
  short* hbufb = (short*)(ws + oR1 + 5242880);
  float* headS = ws + oR1 + 7340032;              // [4096][60] after layers (hbufb dead)
  float* dpS   = ws + oR1 + 7585792;
  float* csum  = ws + oS;
  float* Cpart = ws + oS;
  float* Cp2   = ws + oS;                          // 2-slab partials (out-proj / ff2)
  float* offp  = ws + oOff;
  float* tok   = ws + oTok;
  short* tokb  = (short*)(ws + oTokb);
  float* tok2  = ws + oTok2;
  short* tok2b = (short*)(ws + oTok2b);
  short* Wcatb = (short*)(ws + oWcat);
  float* bcat  = ws + oBcat;
  short* Wq    = (short*)(ws + oWq);
  short* Wo    = (short*)(ws + oWo);
  short* Wf1   = (short*)(ws + oWf1);
  short* Wf2   = (short*)(ws + oWf2);
  short* Whead = (short*)(ws + oWcls);            // cls||det rows: [60][512]
  float* tot   = ws + oTot;
  float* bhead = ws + oBhead;
  int*   sidx  = (int*)(ws + oSidx);

  // merged scan | sort | weight-prep (256 + 8 + 3088 blocks, 512 threads; prep vectorized x4)
  k0<<<3352, 512, 0, stream>>>(x, boxes, proj_w, pos_w2, qkv_w, out_w, ff1_w, ff2_w,
                               cls_w, det_w, proj_b, pos_b2, cls_b, det_b,
                               csum, tot, sidx, out, Wcatb, Wq, bcat, bhead);
  koff<<<16, 256, 0, stream>>>(tot, offp);
  // SPP pooling (zero-LDS, dedup'd rows, uniform reciprocals)
  kspp<<<BDIM * PDIM, 256, 0, stream>>>(csum, offp, boxes, sidx, pos_w1, pos_b1, Abf);

  // G1 split-K-4 x BN=64, XCD-swizzled: 1024 blocks (4/CU)
  gemm_bt<64, 1><<<dim3(8, 32, 4), 256, 0, stream>>>(
      4096, 512, 1024, Abf, 4096, 1024, 0, Wcatb, 4096, 1024, 0,
      Cpart, nullptr, 512, 2097152, 0, 1, 1.f, nullptr, nullptr, 0, nullptr);
  kredG1<<<2048, 256, 0, stream>>>(Cpart, bcat, tok, tokb);

  for (int l = 0; l < 2; ++l){
    const short* qw  = Wq  + (size_t)l * 1536 * 512;
    const short* ow  = Wo  + (size_t)l * 512 * 512;
    const short* f1w = Wf1 + (size_t)l * 1024 * 512;
    const short* f2w = Wf2 + (size_t)l * 512 * 1024;
    const float* qb  = qkv_b + (size_t)l * 1536;
    const float* obv = out_b + (size_t)l * 512;
    const float* f1b = ff1_b + (size_t)l * 1024;
    const float* f2b_ = ff2_b + (size_t)l * 512;

    // qkv = tok @ qkv_w^T + qkv_b   [4096, 1536] (bf16; 768 blocks, 3/CU)
    // V-columns blocks (bx>=16) write transposed directly into Vt (kvt fused away)
    gemm_bt<64><<<dim3(24, 32, 1), 256, 0, stream>>>(
        4096, 1536, 512, tokb, 512, 0, 0, qw, 512, 0, 0,
        nullptr, qkvb, 1536, 0, 0, 1, 1.f, qb, nullptr, 0, Vt);
    // fused flash attention (split-KV, 1024 blocks) -> obufb[b][q][h*128+d]
    kflash<<<1024, 256, 0, stream>>>(qkvb, Vt, obufb);
    // out-proj split-K-2 (512 blocks), then fused reduce+bias+resid+LN1
    gemm_bt<64><<<dim3(8, 32, 2), 256, 0, stream>>>(
        4096, 512, 256, obufb, 512, 256, 0, ow, 512, 256, 0,
        Cp2, nullptr, 512, 2097152, 0, 1, 1.f, nullptr, nullptr, 0, nullptr);
    klnR<<<1024, 256, 0, stream>>>(Cp2, obv, tok, ln1_g + l * 512, ln1_b + l * 512, tok2, tok2b);
    // hbuf = gelu(tok2 @ ff1^T + b1) (bf16; 512 blocks)
    gemm_bt<64><<<dim3(16, 32, 1), 256, 0, stream>>>(
        4096, 1024, 512, tok2b, 512, 0, 0, f1w, 512, 0, 0,
        nullptr, hbufb, 1024, 0, 0, 1, 1.f, f1b, nullptr, 1, nullptr);
    // ff2 split-K-2 (512 blocks), then fused reduce+bias+resid+LN2
    gemm_bt<64><<<dim3(8, 32, 2), 256, 0, stream>>>(
        4096, 512, 512, hbufb, 1024, 512, 0, f2w, 1024, 512, 0,
        Cp2, nullptr, 512, 2097152, 0, 1, 1.f, nullptr, nullptr, 0, nullptr);
    klnR<<<1024, 256, 0, stream>>>(Cp2, f2b_, tok2, ln2_g + l * 512, ln2_b + l * 512, tok, tokb);
  }

  // fused heads: headS[4096][60] = tok @ [cls_w;det_w]^T + [cls_b;det_b]
  gemm_bt<64><<<dim3(1, 32, 1), 256, 0, stream>>>(
      4096, 60, 512, tokb, 512, 0, 0, Whead, 512, 0, 0,
      headS, nullptr, 60, 0, 0, 1, 1.f, bhead, nullptr, 0, nullptr);
  kdetsm<<<BDIM * NCOUT, 64, 0, stream>>>(headS, dpS);
  kfinal<<<1024, 256, 0, stream>>>(headS, dpS, tok, sidx, out);
}

// Round 12
// 470.085 us; speedup vs baseline: 1.0727x; 1.0149x over previous
//
#include <hip/hip_runtime.h>

#define TDIM 2048
#define CDIM 512
#define BDIM 8
#define PDIM 512
#define DMODEL 512
#define NCOUT 30
#define SPPOUT 3584
#define AKDIM 4096   // SPPOUT + DMODEL

typedef __attribute__((ext_vector_type(8))) short short8;
typedef __attribute__((ext_vector_type(4))) short short4v;
typedef __attribute__((ext_vector_type(2))) short short2v;
typedef __attribute__((ext_vector_type(4))) float f32x4;

typedef const __attribute__((address_space(1))) void* as1cv;
typedef __attribute__((address_space(3))) void* as3v;

// async global->LDS, 16B per lane; LDS dest must be wave-uniform base + lane*16
__device__ __forceinline__ void gl_lds16(const short* g, short* l){
  __builtin_amdgcn_global_load_lds((as1cv)g, (as3v)l, 16, 0, 0);
}

__device__ __forceinline__ short f2b(float f){
  unsigned u = __float_as_uint(f);
  unsigned r = (u + 0x7fffu + ((u >> 16) & 1u)) >> 16;
  return (short)r;
}

__device__ __forceinline__ float waveSum(float v){
#pragma unroll
  for (int o = 32; o > 0; o >>= 1) v += __shfl_xor(v, o);
  return v;
}
__device__ __forceinline__ float waveMax(float v){
#pragma unroll
  for (int o = 32; o > 0; o >>= 1) v = fmaxf(v, __shfl_xor(v, o));
  return v;
}

// ---- merged front kernel: blocks [0,256) scan | [256,264) sort | [264,..) weight prep ----
// scan: 32 chunks of 64 along T (1 block/CU): csum[b][t][c], tot[b][ch][c]
// prep: float4/short4 vectorized (all section boundaries 4-aligned)
__global__ __launch_bounds__(512) void k0(
    const float* __restrict__ x, const int* __restrict__ boxes,
    const float* __restrict__ pw, const float* __restrict__ pw2,
    const float* __restrict__ qw, const float* __restrict__ ow,
    const float* __restrict__ f1, const float* __restrict__ f2,
    const float* __restrict__ cl, const float* __restrict__ dt,
    const float* __restrict__ pb, const float* __restrict__ pb2,
    const float* __restrict__ cb, const float* __restrict__ db,
    float* __restrict__ W, float* __restrict__ tot,
    int* __restrict__ sidx, float* __restrict__ out,
    short* __restrict__ Wc, short* __restrict__ Wd,
    float* __restrict__ bc, float* __restrict__ bh)
{
  __shared__ unsigned key[PDIM];
  int blk = blockIdx.x, t = threadIdx.x;
  if (blk < 256){
    int b = blk >> 5, ch = blk & 31;
    int c = t;
    const float* xp = x + ((size_t)(b * CDIM + c)) * TDIM + ch * 64;
    float* wp = W + ((size_t)b * TDIM + ch * 64) * CDIM + c;
    float run = 0.f;
    for (int tl = 0; tl < 64; tl += 4){
      float4 v = *(const float4*)(xp + tl);
      run += v.x; wp[(size_t)(tl + 0) * CDIM] = run;
      run += v.y; wp[(size_t)(tl + 1) * CDIM] = run;
      run += v.z; wp[(size_t)(tl + 2) * CDIM] = run;
      run += v.w; wp[(size_t)(tl + 3) * CDIM] = run;
    }
    tot[((size_t)b * 32 + ch) * CDIM + c] = run;
  } else if (blk < 264){
    int b = blk - 256;
    if (b == 0 && t < 240) out[t] = 0.f;
    int s = boxes[(size_t)(b * PDIM + t) * 2];
    int e = boxes[(size_t)(b * PDIM + t) * 2 + 1];
    key[t] = ((unsigned)(s + e) << 9) | (unsigned)t;
    __syncthreads();
    for (int k = 2; k <= PDIM; k <<= 1){
      for (int j = k >> 1; j > 0; j >>= 1){
        int ixj = t ^ j;
        if (ixj > t){
          unsigned a = key[t], c2 = key[ixj];
          bool up = ((t & k) == 0);
          bool doswap = up ? (a > c2) : (a < c2);
          if (doswap){ key[t] = c2; key[ixj] = a; }
        }
        __syncthreads();
      }
    }
    sidx[b * PDIM + t] = (int)(key[t] & 511u);
  } else {
    int i4 = (blk - 264) * 512 + t;
    if (i4 < 524288){                       // Wc: elements [0, 2097152), 4 per slot
      int base = i4 * 4;
      int r = base >> 12, k = base & 4095;
      float4 v;
      if (k < SPPOUT) v = *(const float4*)(pw + (size_t)r * SPPOUT + k);
      else            v = *(const float4*)(pw2 + (size_t)r * DMODEL + (k - SPPOUT));
      short4v s = { f2b(v.x), f2b(v.y), f2b(v.z), f2b(v.w) };
      *(short4v*)(Wc + base) = s;
    } else if (i4 < 1580544){               // Wd: j in [0, 4225024), 4 per slot
      int j = i4 * 4 - 2097152;
      const float* src; int off;
      if (j < 1572864){ src = qw; off = j; }
      else if (j < 2097152){ src = ow; off = j - 1572864; }
      else if (j < 3145728){ src = f1; off = j - 2097152; }
      else if (j < 4194304){ src = f2; off = j - 3145728; }
      else if (j < 4209664){ src = cl; off = j - 4194304; }
      else { src = dt; off = j - 4209664; }
      float4 v = *(const float4*)(src + off);
      short4v s = { f2b(v.x), f2b(v.y), f2b(v.z), f2b(v.w) };
      *(short4v*)(Wd + j) = s;
    } else if (i4 < 1580688){               // biases: k in [0,576)
      int k = (i4 - 1580544) * 4;
#pragma unroll
      for (int u = 0; u < 4; ++u){
        int kk = k + u;
        if (kk < 512) bc[kk] = pb[kk] + pb2[kk];
        else if (kk < 572) bh[kk - 512] = (kk < 542) ? cb[kk - 512] : db[kk - 542];
      }
    }
  }
}

// exclusive prefix of per-chunk totals -> off[b][ch][c], 32 chunks
__global__ void koff(const float* __restrict__ tot, float* __restrict__ off){
  int b = blockIdx.x >> 1, cg = blockIdx.x & 1;
  int c = cg * 256 + threadIdx.x;
  float run = 0.f;
  for (int ch = 0; ch < 32; ++ch){
    off[((size_t)b * 32 + ch) * CDIM + c] = run;
    run += tot[((size_t)b * 32 + ch) * CDIM + c];
  }
}

// SPP pooling + pos-MLP hidden, staged in sorted order as bf16: A[b][j][0..4095]
// Zero LDS; thread owns cols {2t, 2t+1}: all reads float2/float4, writes short2/4/8.
__global__ void kspp(const float* __restrict__ W, const float* __restrict__ off,
                     const int* __restrict__ boxes, const int* __restrict__ sidx,
                     const float* __restrict__ pw1, const float* __restrict__ pb1,
                     short* __restrict__ A){
  int blk = blockIdx.x;
  int b = blk >> 9, j = blk & 511;
  int p = sidx[b * PDIM + j];
  int s0 = boxes[(size_t)(b * PDIM + p) * 2];
  int e0 = boxes[(size_t)(b * PDIM + p) * 2 + 1];
  int start = min(max(s0, 0), TDIM - 1);
  int end   = min(max(e0, 1), TDIM);
  if (end <= start) end = min(start + 1, TDIM);
  int n = end - start;

  int lo[7], hi[7];
  {
    const int Ls[3] = {1, 2, 4};
    int q = 0;
    for (int li = 0; li < 3; ++li){
      int L = Ls[li];
      for (int i = 0; i < L; ++i){
        lo[q] = start + (i * n) / L;
        hi[q] = start + ((i + 1) * n + L - 1) / L;
        ++q;
      }
    }
  }
  float inv[7];
#pragma unroll
  for (int q = 0; q < 7; ++q) inv[q] = 1.f / (float)(hi[q] - lo[q]);

  // 10 distinct prefix rows; F(-1) = 0. (F(start-1) used 3x, F(end-1) used 3x)
  int R[10] = { start - 1, end - 1, hi[1] - 1, lo[2] - 1, hi[3] - 1,
                lo[4] - 1, hi[4] - 1, lo[5] - 1, hi[5] - 1, lo[6] - 1 };

  float s_f = (float)s0, e_f = (float)e0;
  float px = (s_f + e_f) * 0.5f / (float)TDIM;
  float py = fmaxf(e_f - s_f, 1.f) / (float)TDIM;
  short* Ar = A + (size_t)(b * PDIM + j) * AKDIM;
  const float* Wb = W + (size_t)b * TDIM * CDIM;
  const float* ob = off + (size_t)b * 32 * CDIM;
  int c0 = threadIdx.x * 2;
  float2 F[10];
#pragma unroll
  for (int u = 0; u < 10; ++u){
    int r = R[u];
    if (r < 0){ F[u].x = 0.f; F[u].y = 0.f; }
    else {
      float2 wv = *(const float2*)(Wb + (size_t)r * CDIM + c0);
      float2 ov = *(const float2*)(ob + (r >> 6) * CDIM + c0);
      F[u].x = wv.x + ov.x; F[u].y = wv.y + ov.y;
    }
  }
  // L1
  short2v w1 = { f2b((F[1].x - F[0].x) * inv[0]), f2b((F[1].y - F[0].y) * inv[0]) };
  *(short2v*)(Ar + c0) = w1;
  // L2: [b0(c0), b1(c0), b0(c0+1), b1(c0+1)]
  short4v w2 = { f2b((F[2].x - F[0].x) * inv[1]), f2b((F[1].x - F[3].x) * inv[2]),
                 f2b((F[2].y - F[0].y) * inv[1]), f2b((F[1].y - F[3].y) * inv[2]) };
  *(short4v*)(Ar + 512 + 2 * c0) = w2;
  // L4: [q3..q6 for c0, q3..q6 for c0+1]
  short8 w4 = { f2b((F[4].x - F[0].x) * inv[3]), f2b((F[6].x - F[5].x) * inv[4]),
                f2b((F[8].x - F[7].x) * inv[5]), f2b((F[1].x - F[9].x) * inv[6]),
                f2b((F[4].y - F[0].y) * inv[3]), f2b((F[6].y - F[5].y) * inv[4]),
                f2b((F[8].y - F[7].y) * inv[5]), f2b((F[1].y - F[9].y) * inv[6]) };
  *(short8*)(Ar + 1536 + 4 * c0) = w4;
  // pos-MLP hidden
  float4 pwv = *(const float4*)(pw1 + 2 * c0);
  float2 pbv = *(const float2*)(pb1 + c0);
  float hv0 = pwv.x * px + pwv.y * py + pbv.x;
  float hv1 = pwv.z * px + pwv.w * py + pbv.y;
  short2v wm = { f2b(fmaxf(hv0, 0.f)), f2b(fmaxf(hv1, 0.f)) };
  *(short2v*)(Ar + SPPOUT + c0) = wm;
}

// MFMA bf16 GEMM (nt): C[M,N] = act(alpha * A[M,K] @ B[N,K]^T + bias + resid)
// 128-row tiles, BK=64, XOR-swizzled LDS (conflict-free frag reads).
// SWZ=1: XCD-locality remap (row-chunked, bijective); requires gridDim.y % 8 == 0.
// Vtp: if set and colBase>=1024 (qkv call), the block's output is the V part ->
//      transpose via LDS and store coalesced into Vt[b*4+h][128][512] (skips Cb write).
template<int BN, int SWZ = 0>
__global__ __launch_bounds__(256) void gemm_bt(
    int M, int N, int K,
    const short* __restrict__ A, int lda, long long sAb, long long sAh,
    const short* __restrict__ B, int ldb, long long sBb, long long sBh,
    float* __restrict__ Cf, short* __restrict__ Cb, int ldc, long long sCb, long long sCh,
    int hdiv, float alpha,
    const float* __restrict__ bias, const float* __restrict__ resid, int act,
    short* __restrict__ Vtp)
{
  constexpr int JF = BN / 32;                 // B-frags per wave / B staging batches
  __shared__ short smem[128 * 64 + BN * 64];
  short* As = smem;
  short* Bs = smem + 128 * 64;
  int bx = blockIdx.x, by = blockIdx.y, bz = blockIdx.z;
  if constexpr (SWZ){
    // each XCD owns ny/8 consecutive row-strips across all bx,bz (A-slab L2 reuse)
    int nx = gridDim.x, ny = gridDim.y;
    int rt = ny >> 3;
    int flat = (bz * ny + by) * nx + bx;
    int xcd = flat & 7, wl = flat >> 3;
    by = xcd * rt + wl % rt;
    int rest = wl / rt;
    bx = rest % nx;
    bz = rest / nx;
  }
  int zb = bz / hdiv, zh = bz - zb * hdiv;
  A += (size_t)zb * sAb + (size_t)zh * sAh;
  B += (size_t)zb * sBb + (size_t)zh * sBh;
  size_t coff = (size_t)zb * sCb + (size_t)zh * sCh;
  int rowBase = by * 128, colBase = bx * BN;
  int t = threadIdx.x;
  int lane = t & 63;
  int wave = t >> 6;
  int wm = (wave >> 1) * 64, wn = (wave & 1) * (BN / 2);
  int lm = lane & 15, quad = lane >> 4;
  int srow = t >> 3;
  int skw = ((t & 7) * 8) ^ ((srow & 7) * 8);

  const short* Agp[4];
#pragma unroll
  for (int it = 0; it < 4; ++it)
    Agp[it] = A + (size_t)min(rowBase + srow + it * 32, M - 1) * lda + skw;
  const short* Bgp[JF];
#pragma unroll
  for (int it = 0; it < JF; ++it)
    Bgp[it] = B + (size_t)min(colBase + srow + it * 32, N - 1) * ldb + skw;

  f32x4 zero4 = {0.f, 0.f, 0.f, 0.f};
  f32x4 acc[4][JF];
#pragma unroll
  for (int i = 0; i < 4; ++i)
#pragma unroll
    for (int j = 0; j < JF; ++j) acc[i][j] = zero4;

  int axr = (lm & 7) * 8;
  for (int k0 = 0; k0 < K; k0 += 64){
#pragma unroll
    for (int it = 0; it < 4; ++it) gl_lds16(Agp[it] + k0, As + it * 2048 + t * 8);
#pragma unroll
    for (int it = 0; it < JF; ++it) gl_lds16(Bgp[it] + k0, Bs + it * 2048 + t * 8);
    __syncthreads();
#pragma unroll
    for (int h = 0; h < 2; ++h){
      int koff = (h * 32 + quad * 8) ^ axr;
      short8 af[4], bfr[JF];
#pragma unroll
      for (int i = 0; i < 4; ++i)
        af[i] = *(const short8*)(As + (wm + i * 16 + lm) * 64 + koff);
#pragma unroll
      for (int j = 0; j < JF; ++j)
        bfr[j] = *(const short8*)(Bs + (wn + j * 16 + lm) * 64 + koff);
#pragma unroll
      for (int i = 0; i < 4; ++i)
#pragma unroll
        for (int j = 0; j < JF; ++j)
          acc[i][j] = __builtin_amdgcn_mfma_f32_16x16x32_bf16(af[i], bfr[j], acc[i][j], 0, 0, 0);
    }
    __syncthreads();
  }

  if (Vtp && colBase >= 1024){
    // whole-block V output: bf16-transpose in LDS (pitch 132 kills bank conflicts),
    // then coalesced 64B-per-thread stores into Vt[b*4+h][d][p].
    short* LT = smem;
#pragma unroll
    for (int i = 0; i < 4; ++i){
#pragma unroll
      for (int j = 0; j < JF; ++j){
        int d = wn + j * 16 + lm;
        int prow = wm + i * 16 + quad * 4;
        short4v pk;
#pragma unroll
        for (int r = 0; r < 4; ++r){
          float v = acc[i][j][r] * alpha;
          if (bias) v += bias[colBase + d];
          pk[r] = f2b(v);
        }
        *(short4v*)(LT + d * 132 + prow) = pk;
      }
    }
    __syncthreads();
    int bb = rowBase >> 9;
    int hh = (colBase - 1024) >> 7;
    int dd0 = (colBase - 1024) & 127;
    int dl = t >> 2, pl = (t & 3) * 32;
    const short* sp = LT + dl * 132 + pl;
    short* dp = Vtp + ((size_t)(bb * 4 + hh)) * 65536 + (size_t)(dd0 + dl) * 512 + (rowBase & 511) + pl;
#pragma unroll
    for (int u = 0; u < 4; ++u) *(short8*)(dp + u * 8) = *(const short8*)(sp + u * 8);
    return;
  }

#pragma unroll
  for (int i = 0; i < 4; ++i){
#pragma unroll
    for (int j = 0; j < JF; ++j){
#pragma unroll
      for (int r = 0; r < 4; ++r){
        int row = rowBase + wm + i * 16 + quad * 4 + r;
        int col = colBase + wn + j * 16 + lm;
        if (row < M && col < N){
          float v = acc[i][j][r] * alpha;
          if (bias) v += bias[col];
          size_t ci = coff + (size_t)row * ldc + col;
          if (resid) v += resid[ci];
          if (act) v = 0.5f * v * (1.f + erff(v * 0.7071067811865476f));
          if (Cf) Cf[ci] = v;
          if (Cb) Cb[ci] = f2b(v);
        }
      }
    }
  }
}

// reduce 4 split-K partial slabs + bias -> tok f32 + bf16 (float4 per thread)
__global__ void kredG1(const float* __restrict__ part, const float* __restrict__ bias,
                       float* __restrict__ tok, short* __restrict__ tokb){
  int idx = blockIdx.x * 256 + threadIdx.x;   // over (4096*512)/4
  const float4* p = (const float4*)part;
  float4 v0 = p[idx], v1 = p[idx + 524288], v2 = p[idx + 1048576], v3 = p[idx + 1572864];
  float4 bv = ((const float4*)bias)[idx & 127];
  float4 v;
  v.x = v0.x + v1.x + v2.x + v3.x + bv.x;
  v.y = v0.y + v1.y + v2.y + v3.y + bv.y;
  v.z = v0.z + v1.z + v2.z + v3.z + bv.z;
  v.w = v0.w + v1.w + v2.w + v3.w + bv.w;
  ((float4*)tok)[idx] = v;
  short4v s4 = { f2b(v.x), f2b(v.y), f2b(v.z), f2b(v.w) };
  *(short4v*)(tokb + (size_t)idx * 4) = s4;
}

// Fused flash attention, split-KV: 1024 blocks = (qt 0..31 of 16 q-rows) x (bh 0..31).
__global__ __launch_bounds__(256) void kflash(const short* __restrict__ qkvb,
                                              const short* __restrict__ Vt,
                                              short* __restrict__ ob){
  __shared__ float Ofs[4][16][128];           // 32 KB; first 2KB of each wave's quarter aliases P
  __shared__ float Ml[4][16], Ll[4][16], Fw[4][16], Linv[16];
  int bid = blockIdx.x;                       // qt*32 + bh (same-bh blocks 32 apart -> same XCD)
  int bh = bid & 31, qt = bid >> 5;
  int b = bh >> 2, h = bh & 3;
  int t = threadIdx.x;
  int w = t >> 6, lane = t & 63;
  int lm = lane & 15, quad = lane >> 4;
  const float SL2 = 0.1275174468f;            // 1/sqrt(128) * log2(e)

  const short* qbase = qkvb + (size_t)(b * 512 + qt * 16 + lm) * 1536 + h * 128 + quad * 8;
  short8 qf[4];
#pragma unroll
  for (int s = 0; s < 4; ++s) qf[s] = *(const short8*)(qbase + s * 32);

  const short* kbase = qkvb + (size_t)(b * 512) * 1536 + 512 + h * 128 + quad * 8;
  const short* vbase = Vt + (size_t)bh * 65536 + (size_t)lm * 512 + quad * 8;

  f32x4 zero4 = {0.f, 0.f, 0.f, 0.f};
  f32x4 Of[8];
#pragma unroll
  for (int i = 0; i < 8; ++i) Of[i] = zero4;
  float mrun[4] = {-1e30f, -1e30f, -1e30f, -1e30f};
  float lrun[4] = {0.f, 0.f, 0.f, 0.f};
  short* Pw = (short*)&Ofs[w][0][0];          // 16x64 bf16 = 2KB, wave-private

#pragma unroll
  for (int kt = 0; kt < 2; ++kt){
    int kb = w * 128 + kt * 64;
    f32x4 Sf[4];
#pragma unroll
    for (int j = 0; j < 4; ++j) Sf[j] = zero4;
#pragma unroll
    for (int s = 0; s < 4; ++s){
#pragma unroll
      for (int j = 0; j < 4; ++j){
        short8 kf = *(const short8*)(kbase + (size_t)(kb + j * 16 + lm) * 1536 + s * 32);
        Sf[j] = __builtin_amdgcn_mfma_f32_16x16x32_bf16(qf[s], kf, Sf[j], 0, 0, 0);
      }
    }
    float alpha[4];
#pragma unroll
    for (int r = 0; r < 4; ++r){
      float mx = fmaxf(fmaxf(Sf[0][r], Sf[1][r]), fmaxf(Sf[2][r], Sf[3][r])) * SL2;
#pragma unroll
      for (int o = 1; o < 16; o <<= 1) mx = fmaxf(mx, __shfl_xor(mx, o));
      float mnew = fmaxf(mrun[r], mx);
      alpha[r] = exp2f(mrun[r] - mnew);
      float psum = 0.f;
#pragma unroll
      for (int j = 0; j < 4; ++j){
        float p = exp2f(Sf[j][r] * SL2 - mnew);
        Sf[j][r] = p;
        psum += p;
      }
#pragma unroll
      for (int o = 1; o < 16; o <<= 1) psum += __shfl_xor(psum, o);
      lrun[r] = lrun[r] * alpha[r] + psum;
      mrun[r] = mnew;
    }
#pragma unroll
    for (int i = 0; i < 8; ++i)
#pragma unroll
      for (int r = 0; r < 4; ++r) Of[i][r] *= alpha[r];
#pragma unroll
    for (int j = 0; j < 4; ++j)
#pragma unroll
      for (int r = 0; r < 4; ++r){
        int q = quad * 4 + r;
        int key = j * 16 + lm;
        Pw[q * 64 + (key ^ ((q & 7) * 8))] = f2b(Sf[j][r]);
      }
#pragma unroll
    for (int ts = 0; ts < 2; ++ts){
      short8 pa = *(const short8*)(Pw + lm * 64 + (((ts * 32 + quad * 8) ^ ((lm & 7) * 8))));
#pragma unroll
      for (int jd = 0; jd < 8; ++jd){
        short8 vf = *(const short8*)(vbase + (size_t)(jd * 16) * 512 + kb + ts * 32);
        Of[jd] = __builtin_amdgcn_mfma_f32_16x16x32_bf16(pa, vf, Of[jd], 0, 0, 0);
      }
    }
  }

#pragma unroll
  for (int jd = 0; jd < 8; ++jd)
#pragma unroll
    for (int r = 0; r < 4; ++r)
      Ofs[w][quad * 4 + r][jd * 16 + lm] = Of[jd][r];
  if (lm == 0){
#pragma unroll
    for (int r = 0; r < 4; ++r){
      Ml[w][quad * 4 + r] = mrun[r];
      Ll[w][quad * 4 + r] = lrun[r];
    }
  }
  __syncthreads();

  if (t < 64){
    int wv = t >> 4, row = t & 15;
    float M = fmaxf(fmaxf(Ml[0][row], Ml[1][row]), fmaxf(Ml[2][row], Ml[3][row]));
    Fw[wv][row] = exp2f(Ml[wv][row] - M);
    if (wv == 0){
      float lsum = Ll[0][row] * exp2f(Ml[0][row] - M) + Ll[1][row] * exp2f(Ml[1][row] - M)
                 + Ll[2][row] * exp2f(Ml[2][row] - M) + Ll[3][row] * exp2f(Ml[3][row] - M);
      Linv[row] = 1.f / lsum;
    }
  }
  __syncthreads();

  {
    int row = t >> 4, dbase = (t & 15) * 8;
    float f0 = Fw[0][row], f1 = Fw[1][row], f2v = Fw[2][row], f3 = Fw[3][row];
    float li = Linv[row];
    short* dst = ob + ((size_t)(b * 512 + qt * 16 + row)) * 512 + h * 128 + dbase;
#pragma unroll
    for (int u = 0; u < 8; ++u){
      float v = Ofs[0][row][dbase + u] * f0 + Ofs[1][row][dbase + u] * f1
              + Ofs[2][row][dbase + u] * f2v + Ofs[3][row][dbase + u] * f3;
      dst[u] = f2b(v * li);
    }
  }
}

// fused: reduce 2 split-K slabs + bias + residual + LayerNorm -> f32 + bf16
// 256-thread blocks, 4 rows per block (one per wave)
__global__ __launch_bounds__(256) void klnR(const float* __restrict__ part,
                     const float* __restrict__ bias,
                     const float* __restrict__ resid,
                     const float* __restrict__ g, const float* __restrict__ bb,
                     float* __restrict__ Yf, short* __restrict__ Yb){
  int row = blockIdx.x * 4 + (threadIdx.x >> 6), lane = threadIdx.x & 63;
  size_t base = (size_t)row * DMODEL;
  float v[8]; float s = 0.f;
#pragma unroll
  for (int i = 0; i < 8; ++i){
    int c = lane + 64 * i;
    v[i] = part[base + c] + part[base + c + 2097152] + bias[c] + resid[base + c];
    s += v[i];
  }
  s = waveSum(s);
  float m = s * (1.f / DMODEL);
  float q = 0.f;
#pragma unroll
  for (int i = 0; i < 8; ++i){ float d = v[i] - m; q += d * d; }
  q = waveSum(q);
  float inv = rsqrtf(q * (1.f / DMODEL) + 1e-5f);
#pragma unroll
  for (int i = 0; i < 8; ++i){
    int c = lane + 64 * i;
    float o = (v[i] - m) * inv * g[c] + bb[c];
    Yf[base + c] = o;
    Yb[base + c] = f2b(o);
  }
}

// det softmax stats over P (columns) of headS [4096][60] det part ->
// per-(b,c) max and inverse-sum (kfinal reconstructs the softmax value inline)
__global__ void kdetsm(const float* __restrict__ hd, float* __restrict__ dp){
  int b = blockIdx.x / NCOUT, c = blockIdx.x % NCOUT, lane = threadIdx.x;
  float v[8]; float m = -1e30f;
#pragma unroll
  for (int i = 0; i < 8; ++i){
    v[i] = hd[((size_t)(b * PDIM) + lane + 64 * i) * 60 + 30 + c];
    m = fmaxf(m, v[i]);
  }
  m = waveMax(m);
  float s = 0.f;
#pragma unroll
  for (int i = 0; i < 8; ++i){ s += expf(v[i] - m); }
  s = waveSum(s);
  if (lane == 0){
    dp[b * NCOUT + c] = m;
    dp[240 + b * NCOUT + c] = 1.f / s;
  }
}

// class softmax + joint + scatter back to original order + ctx copy + video accumulation
// 256-thread blocks, 4 (b,j) per block (one per wave)
__global__ __launch_bounds__(256) void kfinal(const float* __restrict__ hd,
                       const float* __restrict__ dps,
                       const float* __restrict__ tok, const int* __restrict__ sidx,
                       float* __restrict__ out){
  int blk = blockIdx.x * 4 + (threadIdx.x >> 6);
  int b = blk >> 9, j = blk & 511;
  int lane = threadIdx.x & 63;
  int p = sidx[b * PDIM + j];
  float* video = out;
  float* joint = out + 240;
  float* clso  = out + 123120;
  float* deto  = out + 246000;
  float* ctxo  = out + 368880;
  size_t rs60 = (size_t)(b * PDIM + j) * 60;
  size_t ro = (size_t)(b * PDIM + p) * NCOUT;
  float lc = (lane < NCOUT) ? hd[rs60 + lane] : -1e30f;
  float m = waveMax(lc);
  float e = (lane < NCOUT) ? expf(lc - m) : 0.f;
  float s = waveSum(e);
  float cp = e / s;
  if (lane < NCOUT){
    float dv  = hd[rs60 + 30 + lane];
    float dpv = expf(dv - dps[b * NCOUT + lane]) * dps[240 + b * NCOUT + lane];
    float jp  = cp * dpv;
    clso[ro + lane] = lc;
    deto[ro + lane] = dv;
    joint[ro + lane] = jp;
    atomicAdd(&video[b * NCOUT + lane], jp);
  }
  const float4* tr = (const float4*)(tok + (size_t)(b * PDIM + j) * DMODEL);
  float4* cr = (float4*)(ctxo + (size_t)(b * PDIM + p) * DMODEL);
  for (int c = lane; c < DMODEL / 4; c += 64) cr[c] = tr[c];
}

extern "C" void kernel_launch(void* const* d_in, const int* in_sizes, int n_in,
                              void* d_out, int out_size, void* d_ws, size_t ws_size,
                              hipStream_t stream) {
  const float* x      = (const float*)d_in[0];
  const int*   boxes  = (const int*)d_in[1];
  const float* proj_w = (const float*)d_in[2];
  const float* proj_b = (const float*)d_in[3];
  const float* pos_w1 = (const float*)d_in[4];
  const float* pos_b1 = (const float*)d_in[5];
  const float* pos_w2 = (const float*)d_in[6];
  const float* pos_b2 = (const float*)d_in[7];
  const float* qkv_w  = (const float*)d_in[8];
  const float* qkv_b  = (const float*)d_in[9];
  const float* out_w  = (const float*)d_in[10];
  const float* out_b  = (const float*)d_in[11];
  const float* ln1_g  = (const float*)d_in[12];
  const float* ln1_b  = (const float*)d_in[13];
  const float* ff1_w  = (const float*)d_in[14];
  const float* ff1_b  = (const float*)d_in[15];
  const float* ff2_w  = (const float*)d_in[16];
  const float* ff2_b  = (const float*)d_in[17];
  const float* ln2_g  = (const float*)d_in[18];
  const float* ln2_b  = (const float*)d_in[19];
  const float* cls_w  = (const float*)d_in[20];
  const float* cls_b  = (const float*)d_in[21];
  const float* det_w  = (const float*)d_in[22];
  const float* det_b  = (const float*)d_in[23];
  float* out = (float*)d_out;
  float* ws  = (float*)d_ws;

  // ---- workspace layout (FLOAT units) ----
  const size_t oR1    = 0;
  const size_t oS     = 9437184;    // csum (8.39M fl), then G1/out-proj/ff2 partials
  const size_t oOff   = 17825792;   // 131,072 fl (tail of oS region, past csum/partials)
  const size_t oTok   = 22020096;   // 2,097,152 fl
  const size_t oTokb  = 24117248;   // 1,048,576 fl
  const size_t oTok2  = 25165824;   // 2,097,152 fl
  const size_t oTok2b = 27262976;   // 1,048,576 fl
  const size_t oWcat  = 28311552;   // 1,048,576 fl
  const size_t oBcat  = 29360128;   // 512 fl
  const size_t oWq    = 29360640;   // k0 prep dest base; contiguous qkv|out|ff1|ff2|cls|det
  const size_t oWo    = 30147072;
  const size_t oWf1   = 30409216;
  const size_t oWf2   = 30933504;
  const size_t oWcls  = 31457792;
  const size_t oTot   = 31473152;   // 131,072 fl (32 chunks)
  const size_t oBhead = 31604224;   // 576 fl
  const size_t oSidx  = 31608320;   // int[4096]

  short* Abf   = (short*)(ws + oR1);
  short* qkvb  = (short*)(ws + oR1);
  short* Vt    = (short*)(ws + oR1 + 3145728);
  short* obufb = (short*)(ws + oR1 + 4194304);
  short* hbufb = (short*)(ws + oR1 + 5242880);
  float* headS = ws + oR1 + 7340032;              // [4096][60] after layers (hbufb dead)
  float* dpS   = ws + oR1 + 7585792;
  float* csum  = ws + oS;
  float* Cpart = ws + oS;
  float* Cp2   = ws + oS;                          // 2-slab partials (out-proj / ff2)
  float* offp  = ws + oOff;
  float* tok   = ws + oTok;
  short* tokb  = (short*)(ws + oTokb);
  float* tok2  = ws + oTok2;
  short* tok2b = (short*)(ws + oTok2b);
  short* Wcatb = (short*)(ws + oWcat);
  float* bcat  = ws + oBcat;
  short* Wq    = (short*)(ws + oWq);
  short* Wo    = (short*)(ws + oWo);
  short* Wf1   = (short*)(ws + oWf1);
  short* Wf2   = (short*)(ws + oWf2);
  short* Whead = (short*)(ws + oWcls);            // cls||det rows: [60][512]
  float* tot   = ws + oTot;
  float* bhead = ws + oBhead;
  int*   sidx  = (int*)(ws + oSidx);

  // merged scan | sort | weight-prep (256 + 8 + 3088 blocks, 512 threads; prep vectorized x4)
  k0<<<3352, 512, 0, stream>>>(x, boxes, proj_w, pos_w2, qkv_w, out_w, ff1_w, ff2_w,
                               cls_w, det_w, proj_b, pos_b2, cls_b, det_b,
                               csum, tot, sidx, out, Wcatb, Wq, bcat, bhead);
  koff<<<16, 256, 0, stream>>>(tot, offp);
  // SPP pooling (zero-LDS, dedup'd rows, fully vectorized)
  kspp<<<BDIM * PDIM, 256, 0, stream>>>(csum, offp, boxes, sidx, pos_w1, pos_b1, Abf);

  // G1 split-K-4 x BN=64, XCD-swizzled: 1024 blocks (4/CU)
  gemm_bt<64, 1><<<dim3(8, 32, 4), 256, 0, stream>>>(
      4096, 512, 1024, Abf, 4096, 1024, 0, Wcatb, 4096, 1024, 0,
      Cpart, nullptr, 512, 2097152, 0, 1, 1.f, nullptr, nullptr, 0, nullptr);
  kredG1<<<2048, 256, 0, stream>>>(Cpart, bcat, tok, tokb);

  for (int l = 0; l < 2; ++l){
    const short* qw  = Wq  + (size_t)l * 1536 * 512;
    const short* ow  = Wo  + (size_t)l * 512 * 512;
    const short* f1w = Wf1 + (size_t)l * 1024 * 512;
    const short* f2w = Wf2 + (size_t)l * 512 * 1024;
    const float* qb  = qkv_b + (size_t)l * 1536;
    const float* obv = out_b + (size_t)l * 512;
    const float* f1b = ff1_b + (size_t)l * 1024;
    const float* f2b_ = ff2_b + (size_t)l * 512;

    // qkv = tok @ qkv_w^T + qkv_b   [4096, 1536] (bf16; 768 blocks, 3/CU)
    // V-columns blocks (bx>=16) write transposed directly into Vt (kvt fused away)
    gemm_bt<64><<<dim3(24, 32, 1), 256, 0, stream>>>(
        4096, 1536, 512, tokb, 512, 0, 0, qw, 512, 0, 0,
        nullptr, qkvb, 1536, 0, 0, 1, 1.f, qb, nullptr, 0, Vt);
    // fused flash attention (split-KV, 1024 blocks) -> obufb[b][q][h*128+d]
    kflash<<<1024, 256, 0, stream>>>(qkvb, Vt, obufb);
    // out-proj split-K-2 (512 blocks), then fused reduce+bias+resid+LN1
    gemm_bt<64><<<dim3(8, 32, 2), 256, 0, stream>>>(
        4096, 512, 256, obufb, 512, 256, 0, ow, 512, 256, 0,
        Cp2, nullptr, 512, 2097152, 0, 1, 1.f, nullptr, nullptr, 0, nullptr);
    klnR<<<1024, 256, 0, stream>>>(Cp2, obv, tok, ln1_g + l * 512, ln1_b + l * 512, tok2, tok2b);
    // hbuf = gelu(tok2 @ ff1^T + b1) (bf16; 512 blocks)
    gemm_bt<64><<<dim3(16, 32, 1), 256, 0, stream>>>(
        4096, 1024, 512, tok2b, 512, 0, 0, f1w, 512, 0, 0,
        nullptr, hbufb, 1024, 0, 0, 1, 1.f, f1b, nullptr, 1, nullptr);
    // ff2 split-K-2 (512 blocks), then fused reduce+bias+resid+LN2
    gemm_bt<64><<<dim3(8, 32, 2), 256, 0, stream>>>(
        4096, 512, 512, hbufb, 1024, 512, 0, f2w, 1024, 512, 0,
        Cp2, nullptr, 512, 2097152, 0, 1, 1.f, nullptr, nullptr, 0, nullptr);
    klnR<<<1024, 256, 0, stream>>>(Cp2, f2b_, tok2, ln2_g + l * 512, ln2_b + l * 512, tok, tokb);
  }

  // fused heads: headS[4096][60] = tok @ [cls_w;det_w]^T + [cls_b;det_b]
  gemm_bt<64><<<dim3(1, 32, 1), 256, 0, stream>>>(
      4096, 60, 512, tokb, 512, 0, 0, Whead, 512, 0, 0,
      headS, nullptr, 60, 0, 0, 1, 1.f, bhead, nullptr, 0, nullptr);
  kdetsm<<<BDIM * NCOUT, 64, 0, stream>>>(headS, dpS);
  kfinal<<<1024, 256, 0, stream>>>(headS, dpS, tok, sidx, out);
}